// Round 6
// baseline (336.725 us; speedup 1.0000x reference)
//
#include <hip/hip_runtime.h>
#include <math.h>

#define BB 8
#define NN 2048
#define DD 512

typedef _Float16 halfT;
typedef _Float16 half8 __attribute__((ext_vector_type(8)));
typedef _Float16 half4 __attribute__((ext_vector_type(4)));
typedef float f32x4 __attribute__((ext_vector_type(4)));

#define GLOAD16(gp, sp) __builtin_amdgcn_global_load_lds( \
    (const __attribute__((address_space(1))) void*)(gp), \
    (__attribute__((address_space(3))) void*)(sp), 16, 0, 0)

// ---------------------------------------------------------------------------
// W transpose + fp16 split:  WT[e][d] = W[d][e]  ->  (hi, lo) fp16 pairs
// ---------------------------------------------------------------------------
__global__ __launch_bounds__(256) void wsplit_kernel(
    const float* __restrict__ Wq, const float* __restrict__ Wk, const float* __restrict__ Wv,
    _Float16* __restrict__ qhT, _Float16* __restrict__ qlT,
    _Float16* __restrict__ khT, _Float16* __restrict__ klT,
    _Float16* __restrict__ vhT)
{
    __shared__ float t[64][65];
    const int z = blockIdx.z;
    const float* W = (z == 0) ? Wq : ((z == 1) ? Wk : Wv);
    _Float16* Ph = (z == 0) ? qhT : ((z == 1) ? khT : vhT);
    _Float16* Pl = (z == 0) ? qlT : ((z == 1) ? klT : nullptr);
    const int bx = blockIdx.x * 64, by = blockIdx.y * 64;
    const int tid = threadIdx.x;
    #pragma unroll
    for (int i = 0; i < 16; ++i) {
        const int idx = i * 256 + tid;
        const int r = idx >> 6, c = idx & 63;
        t[r][c] = W[(long)(by + r) * 512 + bx + c];
    }
    __syncthreads();
    #pragma unroll
    for (int i = 0; i < 16; ++i) {
        const int idx = i * 256 + tid;
        const int r = idx >> 6, c = idx & 63;
        const float v = t[c][r];
        const _Float16 h = (_Float16)v;
        const long o = (long)(bx + r) * 512 + by + c;
        Ph[o] = h;
        if (z < 2) Pl[o] = (_Float16)(v - (float)h);
    }
}

// ---------------------------------------------------------------------------
// Merged q/k projection: [16384,512] @ WT^T, 3-product fp16 split, 128x128
// tile, BK=32. blockIdx.z selects (query,Wq)->q or (key,Wk)->k.
// ---------------------------------------------------------------------------
__global__ __launch_bounds__(256) void projqk_kernel(
    const float* __restrict__ Af0, const float* __restrict__ Af1,
    const _Float16* __restrict__ B0h, const _Float16* __restrict__ B0l,
    const _Float16* __restrict__ B1h, const _Float16* __restrict__ B1l,
    _Float16* __restrict__ O0h, _Float16* __restrict__ O0l,
    _Float16* __restrict__ O1h, _Float16* __restrict__ O1l)
{
    __shared__ __align__(16) _Float16 smem[4 * 128 * 32];
    _Float16* Ah = smem;
    _Float16* Bh = smem + 4096;
    _Float16* Al = smem + 8192;
    _Float16* Bl = smem + 12288;

    const int z = blockIdx.z;
    const float* Af = z ? Af1 : Af0;
    const _Float16* Bgh = z ? B1h : B0h;
    const _Float16* Bgl = z ? B1l : B0l;
    _Float16* Oh = z ? O1h : O0h;
    _Float16* Ol = z ? O1l : O0l;

    const int tid  = threadIdx.x;
    const int lane = tid & 63;
    const int w    = tid >> 6;
    const int wr   = w >> 1, wc = w & 1;
    const int bm   = blockIdx.y * 128, bn = blockIdx.x * 128;

    f32x4 acc[4][4];
    #pragma unroll
    for (int i = 0; i < 4; ++i)
        #pragma unroll
        for (int j = 0; j < 4; ++j) acc[i][j] = (f32x4)0.0f;

    for (int k0 = 0; k0 < DD; k0 += 32) {
        #pragma unroll
        for (int i = 0; i < 2; ++i) {
            const int c   = i * 256 + w * 64 + lane;
            const int row = c >> 2, sl = c & 3;
            const long g  = (long)(bn + row) * DD + k0 + sl * 8;
            const int lb  = (i * 256 + w * 64) * 8;
            GLOAD16(Bgh + g, Bh + lb);
            GLOAD16(Bgl + g, Bl + lb);
        }
        #pragma unroll
        for (int i = 0; i < 4; ++i) {
            const int c = tid + i * 256;
            const int row = c >> 3, q4 = c & 7;
            const float4 v = *(const float4*)(Af + (long)(bm + row) * DD + k0 + q4 * 4);
            half4 h;
            h[0] = (_Float16)v.x; h[1] = (_Float16)v.y;
            h[2] = (_Float16)v.z; h[3] = (_Float16)v.w;
            *(half4*)&Ah[row * 32 + q4 * 4] = h;
            half4 l;
            l[0] = (_Float16)(v.x - (float)h[0]);
            l[1] = (_Float16)(v.y - (float)h[1]);
            l[2] = (_Float16)(v.z - (float)h[2]);
            l[3] = (_Float16)(v.w - (float)h[3]);
            *(half4*)&Al[row * 32 + q4 * 4] = l;
        }
        __syncthreads();

        half8 ah[4], bh[4], al[4], bl[4];
        #pragma unroll
        for (int f = 0; f < 4; ++f) {
            const int ar = wr * 64 + f * 16 + (lane & 15);
            const int ao = ar * 32 + ((lane >> 4) << 3);
            ah[f] = *(const half8*)&Ah[ao];
            al[f] = *(const half8*)&Al[ao];
            const int br = wc * 64 + f * 16 + (lane & 15);
            const int bo = br * 32 + ((lane >> 4) << 3);
            bh[f] = *(const half8*)&Bh[bo];
            bl[f] = *(const half8*)&Bl[bo];
        }
        #pragma unroll
        for (int i = 0; i < 4; ++i)
            #pragma unroll
            for (int j = 0; j < 4; ++j) {
                acc[i][j] = __builtin_amdgcn_mfma_f32_16x16x32_f16(ah[i], bh[j], acc[i][j], 0, 0, 0);
                acc[i][j] = __builtin_amdgcn_mfma_f32_16x16x32_f16(ah[i], bl[j], acc[i][j], 0, 0, 0);
                acc[i][j] = __builtin_amdgcn_mfma_f32_16x16x32_f16(al[i], bh[j], acc[i][j], 0, 0, 0);
            }
        __syncthreads();
    }

    #pragma unroll
    for (int i = 0; i < 4; ++i) {
        const int rb = bm + wr * 64 + i * 16 + ((lane >> 4) << 2);
        #pragma unroll
        for (int j = 0; j < 4; ++j) {
            const int gc = bn + wc * 64 + j * 16 + (lane & 15);
            #pragma unroll
            for (int r = 0; r < 4; ++r) {
                const float vv = acc[i][j][r];
                const _Float16 h = (_Float16)vv;
                const long o = (long)(rb + r) * DD + gc;
                Oh[o] = h;
                Ol[o] = (_Float16)(vv - (float)h);
            }
        }
    }
}

// ---------------------------------------------------------------------------
// Unified NT GEMM (m97-style) kept for v projection (EPI 1) and AV (EPI 3).
// ---------------------------------------------------------------------------
template<int EPI>
__global__ __launch_bounds__(256) void mm_nt(
    const float* __restrict__ Af,
    const _Float16* __restrict__ Agh,
    const _Float16* __restrict__ Bgh,
    float* __restrict__ Of, _Float16* __restrict__ Oh,
    int N, int K, long sAb, long sBb, long sOb)
{
    constexpr bool A_FP32 = (EPI == 1);

    __shared__ __align__(16) _Float16 smem[2 * 128 * 32];
    _Float16* Ah = smem;
    _Float16* Bh = smem + 4096;

    const int tid  = threadIdx.x;
    const int lane = tid & 63;
    const int w    = tid >> 6;
    const int wr   = w >> 1, wc = w & 1;
    const int z    = blockIdx.z;
    const int bm   = blockIdx.y * 128, bn = blockIdx.x * 128;

    const float* Afz = nullptr;
    const _Float16* Aghz = nullptr;
    if constexpr (A_FP32) { Afz = Af + (long)z * sAb; }
    else { Aghz = Agh + (long)z * sAb; }
    const _Float16* Bghz = Bgh + (long)z * sBb;

    f32x4 acc[4][4];
    #pragma unroll
    for (int i = 0; i < 4; ++i)
        #pragma unroll
        for (int j = 0; j < 4; ++j) acc[i][j] = (f32x4)0.0f;

    for (int k0 = 0; k0 < K; k0 += 32) {
        #pragma unroll
        for (int i = 0; i < 2; ++i) {
            const int c   = i * 256 + w * 64 + lane;
            const int row = c >> 2, sl = c & 3;
            const long g  = (long)(bn + row) * K + k0 + sl * 8;
            const int lb  = (i * 256 + w * 64) * 8;
            GLOAD16(Bghz + g, Bh + lb);
        }
        if constexpr (A_FP32) {
            #pragma unroll
            for (int i = 0; i < 4; ++i) {
                const int c = tid + i * 256;
                const int row = c >> 3, q4 = c & 7;
                const float4 v = *(const float4*)(Afz + (long)(bm + row) * K + k0 + q4 * 4);
                half4 h;
                h[0] = (_Float16)v.x; h[1] = (_Float16)v.y;
                h[2] = (_Float16)v.z; h[3] = (_Float16)v.w;
                *(half4*)&Ah[row * 32 + q4 * 4] = h;
            }
        } else {
            #pragma unroll
            for (int i = 0; i < 2; ++i) {
                const int c   = i * 256 + w * 64 + lane;
                const int row = c >> 2, sl = c & 3;
                const long g  = (long)(bm + row) * K + k0 + sl * 8;
                const int lb  = (i * 256 + w * 64) * 8;
                GLOAD16(Aghz + g, Ah + lb);
            }
        }
        __syncthreads();

        half8 ah[4], bh[4];
        #pragma unroll
        for (int f = 0; f < 4; ++f) {
            const int ar = wr * 64 + f * 16 + (lane & 15);
            const int ao = ar * 32 + ((lane >> 4) << 3);
            ah[f] = *(const half8*)&Ah[ao];
            const int br = wc * 64 + f * 16 + (lane & 15);
            const int bo = br * 32 + ((lane >> 4) << 3);
            bh[f] = *(const half8*)&Bh[bo];
        }
        #pragma unroll
        for (int i = 0; i < 4; ++i)
            #pragma unroll
            for (int j = 0; j < 4; ++j)
                acc[i][j] = __builtin_amdgcn_mfma_f32_16x16x32_f16(ah[i], bh[j], acc[i][j], 0, 0, 0);
        __syncthreads();
    }

    #pragma unroll
    for (int i = 0; i < 4; ++i) {
        const int rb = bm + wr * 64 + i * 16 + ((lane >> 4) << 2);
        #pragma unroll
        for (int j = 0; j < 4; ++j) {
            const int gc = bn + wc * 64 + j * 16 + (lane & 15);
            if constexpr (EPI == 1) {
                half4 hv;
                #pragma unroll
                for (int r = 0; r < 4; ++r) hv[r] = (_Float16)acc[i][j][r];
                const int b = rb >> 11, rIn = rb & 2047;
                *(half4*)&Oh[((long)b * 512 + gc) * 2048 + rIn] = hv;
            } else {
                float* O = Of + (long)z * sOb;
                #pragma unroll
                for (int r = 0; r < 4; ++r)
                    O[(long)(rb + r) * N + gc] = acc[i][j][r];
            }
        }
    }
}

// ---------------------------------------------------------------------------
// scores256 v3: 256x256 tile, 8 waves, BK=32, 3-product fp16-split NT GEMM.
// Ring of 8 x 16KB single-array LDS units (Ah|Al|Bh|Bl per K-tile parity).
// Per K-step, 3 phases: {ds_read operand; lgkmcnt(0); barrier; re-stage that
// unit with tile t+2; setprio + 32 MFMA}. One counted vmcnt(8) per step —
// tile t+2's 8 loads stay in flight ~2 steps, no vmcnt(0) drain (T3+T4).
// ---------------------------------------------------------------------------
__global__ __launch_bounds__(512, 2) void scores256_kernel(
    const halfT* __restrict__ qh, const halfT* __restrict__ ql,
    const halfT* __restrict__ kh, const halfT* __restrict__ kl,
    float* __restrict__ C, const float* __restrict__ si, float scale)
{
    extern __shared__ __align__(16) char smem[];   // 8 units x 16384 B

    const int tid  = threadIdx.x;
    const int lane = tid & 63;
    const int w    = tid >> 6;            // 0..7
    const int wr   = w >> 2, wc = w & 3;  // per-wave output 128 x 64

    // bijective XCD swizzle of the 512-block grid
    int flat = (blockIdx.z << 6) | (blockIdx.y << 3) | blockIdx.x;
    flat = ((flat & 7) << 6) | (flat >> 3);
    const int bx = flat & 7, by = (flat >> 3) & 7, bz = flat >> 6;
    const int bm = by * 256, bn = bx * 256;

    const long zoff = (long)bz * NN * DD;
    const halfT* A_h = qh + zoff;
    const halfT* A_l = ql + zoff;
    const halfT* B_h = kh + zoff;
    const halfT* B_l = kl + zoff;

    // staging: wave covers rows w*16+(lane>>2) and +128; pre-swizzled chunk
    const int s_row   = w * 16 + (lane >> 2);
    const int s_chunk = (lane & 3) ^ ((lane >> 3) & 3);
    const long gA = (long)(bm + s_row) * DD + s_chunk * 8;
    const long gB = (long)(bn + s_row) * DD + s_chunk * 8;
    const int ldst = w * 1024;

#define STAGE_UNIT(P, G, T, S) do { \
        const long _kk = (long)(T) * 32; \
        GLOAD16((P) + (G) + _kk,                  smem + (S) * 16384 + ldst); \
        GLOAD16((P) + (G) + (long)128 * DD + _kk, smem + (S) * 16384 + 8192 + ldst); \
    } while (0)

    // fragment read offset (same involution on the read side)
    const int lr   = lane & 15;
    const int q16  = lane >> 4;
    const int frag = lr * 64 + ((q16 ^ ((lr >> 1) & 3)) << 4);
    const int abase = wr * 8192 + frag;   // within A-unit, + m*1024
    const int bbase = wc * 4096 + frag;   // within B-unit, + n*1024

    f32x4 acc[8][4];
    #pragma unroll
    for (int m = 0; m < 8; ++m)
        #pragma unroll
        for (int n = 0; n < 4; ++n) acc[m][n] = (f32x4)0.0f;

    // prologue: stage tiles 0 (slots 0-3) and 1 (slots 4-7)
    STAGE_UNIT(A_h, gA, 0, 0); STAGE_UNIT(A_l, gA, 0, 1);
    STAGE_UNIT(B_h, gB, 0, 2); STAGE_UNIT(B_l, gB, 0, 3);
    STAGE_UNIT(A_h, gA, 1, 4); STAGE_UNIT(A_l, gA, 1, 5);
    STAGE_UNIT(B_h, gB, 1, 6); STAGE_UNIT(B_l, gB, 1, 7);
    asm volatile("s_waitcnt vmcnt(8)" ::: "memory");
    __builtin_amdgcn_s_barrier();
    __builtin_amdgcn_sched_barrier(0);

    for (int t = 0; t < 16; ++t) {
        const int base = (t & 1) * 4;
        const char* uAh = smem + (size_t)(base + 0) * 16384;
        const char* uAl = smem + (size_t)(base + 1) * 16384;
        const char* uBh = smem + (size_t)(base + 2) * 16384;
        const char* uBl = smem + (size_t)(base + 3) * 16384;
        const bool pf = (t < 14);

        half8 ah[8], bh[4], bl[4];
        // ---- phase 1: ah x bh ----
        #pragma unroll
        for (int n = 0; n < 4; ++n)
            bh[n] = *(const half8*)(uBh + bbase + n * 1024);
        #pragma unroll
        for (int m = 0; m < 8; ++m)
            ah[m] = *(const half8*)(uAh + abase + m * 1024);
        asm volatile("s_waitcnt lgkmcnt(0)" ::: "memory");
        __builtin_amdgcn_sched_barrier(0);
        __builtin_amdgcn_s_barrier();            // Ah,Bh slots now dead
        __builtin_amdgcn_sched_barrier(0);
        if (pf) { STAGE_UNIT(A_h, gA, t + 2, base + 0); STAGE_UNIT(B_h, gB, t + 2, base + 2); }
        __builtin_amdgcn_s_setprio(1);
        #pragma unroll
        for (int m = 0; m < 8; ++m)
            #pragma unroll
            for (int n = 0; n < 4; ++n)
                acc[m][n] = __builtin_amdgcn_mfma_f32_16x16x32_f16(ah[m], bh[n], acc[m][n], 0, 0, 0);
        __builtin_amdgcn_s_setprio(0);

        // ---- phase 2: ah x bl ----
        #pragma unroll
        for (int n = 0; n < 4; ++n)
            bl[n] = *(const half8*)(uBl + bbase + n * 1024);
        asm volatile("s_waitcnt lgkmcnt(0)" ::: "memory");
        __builtin_amdgcn_sched_barrier(0);
        __builtin_amdgcn_s_barrier();            // Bl slot now dead
        __builtin_amdgcn_sched_barrier(0);
        if (pf) STAGE_UNIT(B_l, gB, t + 2, base + 3);
        __builtin_amdgcn_s_setprio(1);
        #pragma unroll
        for (int m = 0; m < 8; ++m)
            #pragma unroll
            for (int n = 0; n < 4; ++n)
                acc[m][n] = __builtin_amdgcn_mfma_f32_16x16x32_f16(ah[m], bl[n], acc[m][n], 0, 0, 0);
        __builtin_amdgcn_s_setprio(0);

        // ---- phase 3: al x bh ----
        half8 al[8];
        #pragma unroll
        for (int m = 0; m < 8; ++m)
            al[m] = *(const half8*)(uAl + abase + m * 1024);
        asm volatile("s_waitcnt lgkmcnt(0)" ::: "memory");
        __builtin_amdgcn_sched_barrier(0);
        __builtin_amdgcn_s_barrier();            // Al slot now dead
        __builtin_amdgcn_sched_barrier(0);
        if (pf) STAGE_UNIT(A_l, gA, t + 2, base + 1);
        __builtin_amdgcn_s_setprio(1);
        #pragma unroll
        for (int m = 0; m < 8; ++m)
            #pragma unroll
            for (int n = 0; n < 4; ++n)
                acc[m][n] = __builtin_amdgcn_mfma_f32_16x16x32_f16(al[m], bh[n], acc[m][n], 0, 0, 0);
        __builtin_amdgcn_s_setprio(0);

        // ---- step end: wait tile t+1 (counted — t+2 stays in flight) ----
        if (t < 15) {
            if (t < 14) { asm volatile("s_waitcnt vmcnt(8)" ::: "memory"); }
            else        { asm volatile("s_waitcnt vmcnt(0)" ::: "memory"); }
            __builtin_amdgcn_s_barrier();
            __builtin_amdgcn_sched_barrier(0);
        }
    }
#undef STAGE_UNIT

    // epilogue: scale + diagonal bias, fp32 store
    float* Cz = C + (long)bz * NN * NN;
    #pragma unroll
    for (int m = 0; m < 8; ++m) {
        const int rb = bm + wr * 128 + m * 16 + ((lane >> 4) << 2);
        #pragma unroll
        for (int n = 0; n < 4; ++n) {
            const int gc = bn + wc * 64 + n * 16 + (lane & 15);
            #pragma unroll
            for (int r = 0; r < 4; ++r) {
                const int gr = rb + r;
                float vv = acc[m][n][r] * scale;
                if (gr == gc) vv += fminf(expf(si[gr]), 3.0f);
                Cz[(long)gr * NN + gc] = vv;
            }
        }
    }
}

// ---------------------------------------------------------------------------
// In-place row softmax + entropy partial + fp16 copy of attn.
// ---------------------------------------------------------------------------
__global__ __launch_bounds__(256) void softmax_entropy_kernel(
    float* __restrict__ attn, _Float16* __restrict__ ah, float* __restrict__ partials)
{
    __shared__ float red[4];
    const long row = blockIdx.x;
    float* p = attn + row * (long)NN;
    _Float16* ph = ah + row * (long)NN;
    const int tid = threadIdx.x;
    const int base = tid * 8;

    float4 va = *(const float4*)(p + base);
    float4 vb = *(const float4*)(p + base + 4);
    float v[8] = {va.x, va.y, va.z, va.w, vb.x, vb.y, vb.z, vb.w};

    float m = v[0];
    #pragma unroll
    for (int i = 1; i < 8; ++i) m = fmaxf(m, v[i]);
    #pragma unroll
    for (int o = 32; o; o >>= 1) m = fmaxf(m, __shfl_xor(m, o, 64));
    if ((tid & 63) == 0) red[tid >> 6] = m;
    __syncthreads();
    m = fmaxf(fmaxf(red[0], red[1]), fmaxf(red[2], red[3]));

    float t[8];
    float s = 0.f;
    #pragma unroll
    for (int i = 0; i < 8; ++i) { t[i] = v[i] - m; v[i] = expf(t[i]); s += v[i]; }
    #pragma unroll
    for (int o = 32; o; o >>= 1) s += __shfl_xor(s, o, 64);
    __syncthreads();
    if ((tid & 63) == 0) red[tid >> 6] = s;
    __syncthreads();
    s = red[0] + red[1] + red[2] + red[3];

    const float inv = 1.0f / s;
    const float lns = logf(s);
    float e = 0.f;
    float pv[8];
    #pragma unroll
    for (int i = 0; i < 8; ++i) {
        pv[i] = v[i] * inv;
        e = fmaf(pv[i], t[i] - lns, e);
    }
    *(float4*)(p + base)     = make_float4(pv[0], pv[1], pv[2], pv[3]);
    *(float4*)(p + base + 4) = make_float4(pv[4], pv[5], pv[6], pv[7]);
    half8 h;
    #pragma unroll
    for (int i = 0; i < 8; ++i) h[i] = (_Float16)pv[i];
    *(half8*)(ph + base) = h;

    #pragma unroll
    for (int o = 32; o; o >>= 1) e += __shfl_xor(e, o, 64);
    __syncthreads();
    if ((tid & 63) == 0) red[tid >> 6] = e;
    __syncthreads();
    if (tid == 0) partials[row] = red[0] + red[1] + red[2] + red[3];
}

__global__ __launch_bounds__(256) void ent_reduce_kernel(
    const float* __restrict__ partials, float* __restrict__ ent)
{
    __shared__ float red[4];
    float s = 0.f;
    for (int i = threadIdx.x; i < BB * NN; i += 256) s += partials[i];
    #pragma unroll
    for (int o = 32; o; o >>= 1) s += __shfl_xor(s, o, 64);
    if ((threadIdx.x & 63) == 0) red[threadIdx.x >> 6] = s;
    __syncthreads();
    if (threadIdx.x == 0)
        *ent = -(red[0] + red[1] + red[2] + red[3]) / (float)(BB * NN);
}

extern "C" void kernel_launch(void* const* d_in, const int* in_sizes, int n_in,
                              void* d_out, int out_size, void* d_ws, size_t ws_size,
                              hipStream_t stream) {
    const float* query = (const float*)d_in[0];
    const float* key   = (const float*)d_in[1];
    const float* value = (const float*)d_in[2];
    const float* Wq    = (const float*)d_in[3];
    const float* Wk    = (const float*)d_in[4];
    const float* Wv    = (const float*)d_in[5];
    const float* si    = (const float*)d_in[6];

    float* out  = (float*)d_out;                        // [B,N,D]
    float* attn = out + (size_t)BB * NN * DD;           // [B,N,N]
    float* ent  = attn + (size_t)BB * NN * NN;          // scalar

    const size_t NK = (size_t)BB * NN * DD;             // 8.39M elements
    _Float16* ws16 = (_Float16*)d_ws;
    _Float16* qh = ws16;            // 16.8 MB each
    _Float16* ql = qh + NK;
    _Float16* kh = ql + NK;
    _Float16* kl = kh + NK;
    _Float16* vT = kl + NK;         // vT fp16 [b][512][2048]
    _Float16* WqhT = vT + NK;       // 0.5 MB each
    _Float16* WqlT = WqhT + DD * DD;
    _Float16* WkhT = WqlT + DD * DD;
    _Float16* WklT = WkhT + DD * DD;
    _Float16* WvhT = WklT + DD * DD;
    float* partials = (float*)(WvhT + DD * DD);         // 64 KB
    _Float16* attn_h = ws16;        // 67 MB, aliases qh..kl (dead after scores)

    const dim3 blk(256);
    const float inv_sqrt_d = 0.044194173824159216f;     // 1/sqrt(512)

    wsplit_kernel<<<dim3(8, 8, 3), blk, 0, stream>>>(Wq, Wk, Wv,
        WqhT, WqlT, WkhT, WklT, WvhT);

    // merged q/k projections (z = 0: query, z = 1: key), 3-product
    projqk_kernel<<<dim3(4, 128, 2), blk, 0, stream>>>(
        query, key, WqhT, WqlT, WkhT, WklT, qh, ql, kh, kl);
    // v projection, 1-product, writes vT fp16
    mm_nt<1><<<dim3(4, 128, 1), blk, 0, stream>>>(
        value, nullptr, WvhT, nullptr, vT, DD, DD, 0, 0, 0);

    // scores = q k^T / sqrt(d) + diag(min(exp(si),3))  [256^2 v3 pipeline]
    scores256_kernel<<<dim3(8, 8, 8), dim3(512), 131072, stream>>>(
        qh, ql, kh, kl, attn, si, inv_sqrt_d);

    softmax_entropy_kernel<<<dim3(BB * NN), blk, 0, stream>>>(attn, attn_h, partials);
    ent_reduce_kernel<<<dim3(1), blk, 0, stream>>>(partials, ent);

    // out = attn @ v : A = attn fp16 [2048][2048], B = vT fp16 [512][2048]
    mm_nt<3><<<dim3(4, 16, BB), blk, 0, stream>>>(
        nullptr, attn_h, vT, out, nullptr, DD, NN,
        (long)NN * NN, (long)DD * NN, (long)NN * DD);
}

// Round 7
// 335.745 us; speedup vs baseline: 1.0029x; 1.0029x over previous
//
#include <hip/hip_runtime.h>
#include <math.h>

#define BB 8
#define NN 2048
#define DD 512

typedef _Float16 halfT;
typedef _Float16 half8 __attribute__((ext_vector_type(8)));
typedef _Float16 half4 __attribute__((ext_vector_type(4)));
typedef float f32x4 __attribute__((ext_vector_type(4)));

#define GLOAD16(gp, sp) __builtin_amdgcn_global_load_lds( \
    (const __attribute__((address_space(1))) void*)(gp), \
    (__attribute__((address_space(3))) void*)(sp), 16, 0, 0)

// ---------------------------------------------------------------------------
// W transpose + fp16 split:  WT[e][d] = W[d][e]  ->  (hi, lo) fp16 pairs
// ---------------------------------------------------------------------------
__global__ __launch_bounds__(256) void wsplit_kernel(
    const float* __restrict__ Wq, const float* __restrict__ Wk, const float* __restrict__ Wv,
    _Float16* __restrict__ qhT, _Float16* __restrict__ qlT,
    _Float16* __restrict__ khT, _Float16* __restrict__ klT,
    _Float16* __restrict__ vhT)
{
    __shared__ float t[64][65];
    const int z = blockIdx.z;
    const float* W = (z == 0) ? Wq : ((z == 1) ? Wk : Wv);
    _Float16* Ph = (z == 0) ? qhT : ((z == 1) ? khT : vhT);
    _Float16* Pl = (z == 0) ? qlT : ((z == 1) ? klT : nullptr);
    const int bx = blockIdx.x * 64, by = blockIdx.y * 64;
    const int tid = threadIdx.x;
    #pragma unroll
    for (int i = 0; i < 16; ++i) {
        const int idx = i * 256 + tid;
        const int r = idx >> 6, c = idx & 63;
        t[r][c] = W[(long)(by + r) * 512 + bx + c];
    }
    __syncthreads();
    #pragma unroll
    for (int i = 0; i < 16; ++i) {
        const int idx = i * 256 + tid;
        const int r = idx >> 6, c = idx & 63;
        const float v = t[c][r];
        const _Float16 h = (_Float16)v;
        const long o = (long)(bx + r) * 512 + by + c;
        Ph[o] = h;
        if (z < 2) Pl[o] = (_Float16)(v - (float)h);
    }
}

// ---------------------------------------------------------------------------
// Merged q/k projection: [16384,512] @ WT^T, 3-product fp16 split, 128x128
// tile, BK=32. blockIdx.z selects (query,Wq)->q or (key,Wk)->k.
// ---------------------------------------------------------------------------
__global__ __launch_bounds__(256) void projqk_kernel(
    const float* __restrict__ Af0, const float* __restrict__ Af1,
    const _Float16* __restrict__ B0h, const _Float16* __restrict__ B0l,
    const _Float16* __restrict__ B1h, const _Float16* __restrict__ B1l,
    _Float16* __restrict__ O0h, _Float16* __restrict__ O0l,
    _Float16* __restrict__ O1h, _Float16* __restrict__ O1l)
{
    __shared__ __align__(16) _Float16 smem[4 * 128 * 32];
    _Float16* Ah = smem;
    _Float16* Bh = smem + 4096;
    _Float16* Al = smem + 8192;
    _Float16* Bl = smem + 12288;

    const int z = blockIdx.z;
    const float* Af = z ? Af1 : Af0;
    const _Float16* Bgh = z ? B1h : B0h;
    const _Float16* Bgl = z ? B1l : B0l;
    _Float16* Oh = z ? O1h : O0h;
    _Float16* Ol = z ? O1l : O0l;

    const int tid  = threadIdx.x;
    const int lane = tid & 63;
    const int w    = tid >> 6;
    const int wr   = w >> 1, wc = w & 1;
    const int bm   = blockIdx.y * 128, bn = blockIdx.x * 128;

    f32x4 acc[4][4];
    #pragma unroll
    for (int i = 0; i < 4; ++i)
        #pragma unroll
        for (int j = 0; j < 4; ++j) acc[i][j] = (f32x4)0.0f;

    for (int k0 = 0; k0 < DD; k0 += 32) {
        #pragma unroll
        for (int i = 0; i < 2; ++i) {
            const int c   = i * 256 + w * 64 + lane;
            const int row = c >> 2, sl = c & 3;
            const long g  = (long)(bn + row) * DD + k0 + sl * 8;
            const int lb  = (i * 256 + w * 64) * 8;
            GLOAD16(Bgh + g, Bh + lb);
            GLOAD16(Bgl + g, Bl + lb);
        }
        #pragma unroll
        for (int i = 0; i < 4; ++i) {
            const int c = tid + i * 256;
            const int row = c >> 3, q4 = c & 7;
            const float4 v = *(const float4*)(Af + (long)(bm + row) * DD + k0 + q4 * 4);
            half4 h;
            h[0] = (_Float16)v.x; h[1] = (_Float16)v.y;
            h[2] = (_Float16)v.z; h[3] = (_Float16)v.w;
            *(half4*)&Ah[row * 32 + q4 * 4] = h;
            half4 l;
            l[0] = (_Float16)(v.x - (float)h[0]);
            l[1] = (_Float16)(v.y - (float)h[1]);
            l[2] = (_Float16)(v.z - (float)h[2]);
            l[3] = (_Float16)(v.w - (float)h[3]);
            *(half4*)&Al[row * 32 + q4 * 4] = l;
        }
        __syncthreads();

        half8 ah[4], bh[4], al[4], bl[4];
        #pragma unroll
        for (int f = 0; f < 4; ++f) {
            const int ar = wr * 64 + f * 16 + (lane & 15);
            const int ao = ar * 32 + ((lane >> 4) << 3);
            ah[f] = *(const half8*)&Ah[ao];
            al[f] = *(const half8*)&Al[ao];
            const int br = wc * 64 + f * 16 + (lane & 15);
            const int bo = br * 32 + ((lane >> 4) << 3);
            bh[f] = *(const half8*)&Bh[bo];
            bl[f] = *(const half8*)&Bl[bo];
        }
        #pragma unroll
        for (int i = 0; i < 4; ++i)
            #pragma unroll
            for (int j = 0; j < 4; ++j) {
                acc[i][j] = __builtin_amdgcn_mfma_f32_16x16x32_f16(ah[i], bh[j], acc[i][j], 0, 0, 0);
                acc[i][j] = __builtin_amdgcn_mfma_f32_16x16x32_f16(ah[i], bl[j], acc[i][j], 0, 0, 0);
                acc[i][j] = __builtin_amdgcn_mfma_f32_16x16x32_f16(al[i], bh[j], acc[i][j], 0, 0, 0);
            }
        __syncthreads();
    }

    #pragma unroll
    for (int i = 0; i < 4; ++i) {
        const int rb = bm + wr * 64 + i * 16 + ((lane >> 4) << 2);
        #pragma unroll
        for (int j = 0; j < 4; ++j) {
            const int gc = bn + wc * 64 + j * 16 + (lane & 15);
            #pragma unroll
            for (int r = 0; r < 4; ++r) {
                const float vv = acc[i][j][r];
                const _Float16 h = (_Float16)vv;
                const long o = (long)(rb + r) * DD + gc;
                Oh[o] = h;
                Ol[o] = (_Float16)(vv - (float)h);
            }
        }
    }
}

// ---------------------------------------------------------------------------
// Unified NT GEMM (m97-style) kept for v projection (EPI 1) and AV (EPI 3).
// ---------------------------------------------------------------------------
template<int EPI>
__global__ __launch_bounds__(256) void mm_nt(
    const float* __restrict__ Af,
    const _Float16* __restrict__ Agh,
    const _Float16* __restrict__ Bgh,
    float* __restrict__ Of, _Float16* __restrict__ Oh,
    int N, int K, long sAb, long sBb, long sOb)
{
    constexpr bool A_FP32 = (EPI == 1);

    __shared__ __align__(16) _Float16 smem[2 * 128 * 32];
    _Float16* Ah = smem;
    _Float16* Bh = smem + 4096;

    const int tid  = threadIdx.x;
    const int lane = tid & 63;
    const int w    = tid >> 6;
    const int wr   = w >> 1, wc = w & 1;
    const int z    = blockIdx.z;
    const int bm   = blockIdx.y * 128, bn = blockIdx.x * 128;

    const float* Afz = nullptr;
    const _Float16* Aghz = nullptr;
    if constexpr (A_FP32) { Afz = Af + (long)z * sAb; }
    else { Aghz = Agh + (long)z * sAb; }
    const _Float16* Bghz = Bgh + (long)z * sBb;

    f32x4 acc[4][4];
    #pragma unroll
    for (int i = 0; i < 4; ++i)
        #pragma unroll
        for (int j = 0; j < 4; ++j) acc[i][j] = (f32x4)0.0f;

    for (int k0 = 0; k0 < K; k0 += 32) {
        #pragma unroll
        for (int i = 0; i < 2; ++i) {
            const int c   = i * 256 + w * 64 + lane;
            const int row = c >> 2, sl = c & 3;
            const long g  = (long)(bn + row) * K + k0 + sl * 8;
            const int lb  = (i * 256 + w * 64) * 8;
            GLOAD16(Bghz + g, Bh + lb);
        }
        if constexpr (A_FP32) {
            #pragma unroll
            for (int i = 0; i < 4; ++i) {
                const int c = tid + i * 256;
                const int row = c >> 3, q4 = c & 7;
                const float4 v = *(const float4*)(Afz + (long)(bm + row) * K + k0 + q4 * 4);
                half4 h;
                h[0] = (_Float16)v.x; h[1] = (_Float16)v.y;
                h[2] = (_Float16)v.z; h[3] = (_Float16)v.w;
                *(half4*)&Ah[row * 32 + q4 * 4] = h;
            }
        } else {
            #pragma unroll
            for (int i = 0; i < 2; ++i) {
                const int c   = i * 256 + w * 64 + lane;
                const int row = c >> 2, sl = c & 3;
                const long g  = (long)(bm + row) * K + k0 + sl * 8;
                const int lb  = (i * 256 + w * 64) * 8;
                GLOAD16(Aghz + g, Ah + lb);
            }
        }
        __syncthreads();

        half8 ah[4], bh[4];
        #pragma unroll
        for (int f = 0; f < 4; ++f) {
            const int ar = wr * 64 + f * 16 + (lane & 15);
            const int ao = ar * 32 + ((lane >> 4) << 3);
            ah[f] = *(const half8*)&Ah[ao];
            const int br = wc * 64 + f * 16 + (lane & 15);
            const int bo = br * 32 + ((lane >> 4) << 3);
            bh[f] = *(const half8*)&Bh[bo];
        }
        #pragma unroll
        for (int i = 0; i < 4; ++i)
            #pragma unroll
            for (int j = 0; j < 4; ++j)
                acc[i][j] = __builtin_amdgcn_mfma_f32_16x16x32_f16(ah[i], bh[j], acc[i][j], 0, 0, 0);
        __syncthreads();
    }

    #pragma unroll
    for (int i = 0; i < 4; ++i) {
        const int rb = bm + wr * 64 + i * 16 + ((lane >> 4) << 2);
        #pragma unroll
        for (int j = 0; j < 4; ++j) {
            const int gc = bn + wc * 64 + j * 16 + (lane & 15);
            if constexpr (EPI == 1) {
                half4 hv;
                #pragma unroll
                for (int r = 0; r < 4; ++r) hv[r] = (_Float16)acc[i][j][r];
                const int b = rb >> 11, rIn = rb & 2047;
                *(half4*)&Oh[((long)b * 512 + gc) * 2048 + rIn] = hv;
            } else {
                float* O = Of + (long)z * sOb;
                #pragma unroll
                for (int r = 0; r < 4; ++r)
                    O[(long)(rb + r) * N + gc] = acc[i][j][r];
            }
        }
    }
}

// ---------------------------------------------------------------------------
// scores256 v4 (m201-style): 256x256 tile, 8 waves, BK=32, 3-product split.
// Double-buffered LDS (2 x 64KB). 3 phases per K-tile, each:
//   { ds_read subtile (in flight) ; issue 4 gload_lds -> OTHER buf ;
//     s_barrier ; lgkmcnt(0)+sched_barrier ; setprio(1) 32 MFMA setprio(0) ;
//     s_barrier }
// LDS-read latency hides behind the barrier; gloads issued in ph0/ph1 get
// ~1000+ cyc of flight, so the single end-of-step vmcnt(0) is nearly free.
// ---------------------------------------------------------------------------
__global__ __launch_bounds__(512, 2) void scores256_kernel(
    const halfT* __restrict__ qh, const halfT* __restrict__ ql,
    const halfT* __restrict__ kh, const halfT* __restrict__ kl,
    float* __restrict__ C, const float* __restrict__ si, float scale)
{
    extern __shared__ __align__(16) char smem[];   // 2 bufs x 65536 B
    // buf layout (byte offsets): Ah 0 | Al 16384 | Bh 32768 | Bl 49152

    const int tid  = threadIdx.x;
    const int lane = tid & 63;
    const int w    = tid >> 6;            // 0..7
    const int wr   = w >> 2, wc = w & 3;  // per-wave output 128 x 64

    // bijective XCD swizzle of the 512-block grid
    int flat = (blockIdx.z << 6) | (blockIdx.y << 3) | blockIdx.x;
    flat = ((flat & 7) << 6) | (flat >> 3);
    const int bx = flat & 7, by = (flat >> 3) & 7, bz = flat >> 6;
    const int bm = by * 256, bn = bx * 256;

    const long zoff = (long)bz * NN * DD;
    const halfT* A_h = qh + zoff;
    const halfT* A_l = ql + zoff;
    const halfT* B_h = kh + zoff;
    const halfT* B_l = kl + zoff;

    // staging: wave covers rows w*16+(lane>>2) and +128; pre-swizzled chunk
    const int s_row   = w * 16 + (lane >> 2);
    const int s_chunk = (lane & 3) ^ ((lane >> 3) & 3);
    const long gA = (long)(bm + s_row) * DD + s_chunk * 8;
    const long gB = (long)(bn + s_row) * DD + s_chunk * 8;
    const int ldst = w * 1024;
    const long rstep = (long)128 * DD;

    // fragment read offset (same involution on the read side)
    const int lr   = lane & 15;
    const int q16  = lane >> 4;
    const int frag = lr * 64 + ((q16 ^ ((lr >> 1) & 3)) << 4);
    const int abase = wr * 8192 + frag;   // within A unit, + m*1024
    const int bbase = wc * 4096 + frag;   // within B unit, + n*1024

    f32x4 acc[8][4];
    #pragma unroll
    for (int m = 0; m < 8; ++m)
        #pragma unroll
        for (int n = 0; n < 4; ++n) acc[m][n] = (f32x4)0.0f;

    // prologue: stage tile 0 -> buf 0
    {
        char* b0 = smem;
        GLOAD16(A_h + gA,         b0 + ldst);
        GLOAD16(A_h + gA + rstep, b0 + 8192 + ldst);
        GLOAD16(A_l + gA,         b0 + 16384 + ldst);
        GLOAD16(A_l + gA + rstep, b0 + 16384 + 8192 + ldst);
        GLOAD16(B_h + gB,         b0 + 32768 + ldst);
        GLOAD16(B_h + gB + rstep, b0 + 32768 + 8192 + ldst);
        GLOAD16(B_l + gB,         b0 + 49152 + ldst);
        GLOAD16(B_l + gB + rstep, b0 + 49152 + 8192 + ldst);
    }
    asm volatile("s_waitcnt vmcnt(0)" ::: "memory");
    __builtin_amdgcn_s_barrier();
    __builtin_amdgcn_sched_barrier(0);

    for (int t = 0; t < 16; ++t) {
        char* cur = smem + (size_t)(t & 1) * 65536;
        char* nxt = smem + (size_t)((t + 1) & 1) * 65536;
        const bool pf = (t < 15);
        const long kk = (long)(t + 1) * 32;

        half8 ah[8], bh[4];
        // ---- phase 0: read ah,bh ; stage next Ah,Al ; MFMA ah*bh ----
        #pragma unroll
        for (int n = 0; n < 4; ++n)
            bh[n] = *(const half8*)(cur + 32768 + bbase + n * 1024);
        #pragma unroll
        for (int m = 0; m < 8; ++m)
            ah[m] = *(const half8*)(cur + abase + m * 1024);
        if (pf) {
            GLOAD16(A_h + gA + kk,         nxt + ldst);
            GLOAD16(A_h + gA + rstep + kk, nxt + 8192 + ldst);
            GLOAD16(A_l + gA + kk,         nxt + 16384 + ldst);
            GLOAD16(A_l + gA + rstep + kk, nxt + 16384 + 8192 + ldst);
        }
        __builtin_amdgcn_s_barrier();
        asm volatile("s_waitcnt lgkmcnt(0)" ::: "memory");
        __builtin_amdgcn_sched_barrier(0);
        __builtin_amdgcn_s_setprio(1);
        #pragma unroll
        for (int m = 0; m < 8; ++m)
            #pragma unroll
            for (int n = 0; n < 4; ++n)
                acc[m][n] = __builtin_amdgcn_mfma_f32_16x16x32_f16(ah[m], bh[n], acc[m][n], 0, 0, 0);
        __builtin_amdgcn_s_setprio(0);
        __builtin_amdgcn_s_barrier();
        __builtin_amdgcn_sched_barrier(0);

        // ---- phase 1: read bl ; stage next Bh,Bl ; MFMA ah*bl ----
        half8 bl[4];
        #pragma unroll
        for (int n = 0; n < 4; ++n)
            bl[n] = *(const half8*)(cur + 49152 + bbase + n * 1024);
        if (pf) {
            GLOAD16(B_h + gB + kk,         nxt + 32768 + ldst);
            GLOAD16(B_h + gB + rstep + kk, nxt + 32768 + 8192 + ldst);
            GLOAD16(B_l + gB + kk,         nxt + 49152 + ldst);
            GLOAD16(B_l + gB + rstep + kk, nxt + 49152 + 8192 + ldst);
        }
        __builtin_amdgcn_s_barrier();
        asm volatile("s_waitcnt lgkmcnt(0)" ::: "memory");
        __builtin_amdgcn_sched_barrier(0);
        __builtin_amdgcn_s_setprio(1);
        #pragma unroll
        for (int m = 0; m < 8; ++m)
            #pragma unroll
            for (int n = 0; n < 4; ++n)
                acc[m][n] = __builtin_amdgcn_mfma_f32_16x16x32_f16(ah[m], bl[n], acc[m][n], 0, 0, 0);
        __builtin_amdgcn_s_setprio(0);
        __builtin_amdgcn_s_barrier();
        __builtin_amdgcn_sched_barrier(0);

        // ---- phase 2: read al ; MFMA al*bh ; end-of-step vmcnt ----
        half8 al[8];
        #pragma unroll
        for (int m = 0; m < 8; ++m)
            al[m] = *(const half8*)(cur + 16384 + abase + m * 1024);
        __builtin_amdgcn_s_barrier();
        asm volatile("s_waitcnt lgkmcnt(0)" ::: "memory");
        __builtin_amdgcn_sched_barrier(0);
        __builtin_amdgcn_s_setprio(1);
        #pragma unroll
        for (int m = 0; m < 8; ++m)
            #pragma unroll
            for (int n = 0; n < 4; ++n)
                acc[m][n] = __builtin_amdgcn_mfma_f32_16x16x32_f16(al[m], bh[n], acc[m][n], 0, 0, 0);
        __builtin_amdgcn_s_setprio(0);
        if (pf) { asm volatile("s_waitcnt vmcnt(0)" ::: "memory"); }
        __builtin_amdgcn_s_barrier();
        __builtin_amdgcn_sched_barrier(0);
    }

    // epilogue: scale + diagonal bias, fp32 store
    float* Cz = C + (long)bz * NN * NN;
    #pragma unroll
    for (int m = 0; m < 8; ++m) {
        const int rb = bm + wr * 128 + m * 16 + ((lane >> 4) << 2);
        #pragma unroll
        for (int n = 0; n < 4; ++n) {
            const int gc = bn + wc * 64 + n * 16 + (lane & 15);
            #pragma unroll
            for (int r = 0; r < 4; ++r) {
                const int gr = rb + r;
                float vv = acc[m][n][r] * scale;
                if (gr == gc) vv += fminf(expf(si[gr]), 3.0f);
                Cz[(long)gr * NN + gc] = vv;
            }
        }
    }
}

// ---------------------------------------------------------------------------
// In-place row softmax + entropy partial + fp16 copy of attn.
// ---------------------------------------------------------------------------
__global__ __launch_bounds__(256) void softmax_entropy_kernel(
    float* __restrict__ attn, _Float16* __restrict__ ah, float* __restrict__ partials)
{
    __shared__ float red[4];
    const long row = blockIdx.x;
    float* p = attn + row * (long)NN;
    _Float16* ph = ah + row * (long)NN;
    const int tid = threadIdx.x;
    const int base = tid * 8;

    float4 va = *(const float4*)(p + base);
    float4 vb = *(const float4*)(p + base + 4);
    float v[8] = {va.x, va.y, va.z, va.w, vb.x, vb.y, vb.z, vb.w};

    float m = v[0];
    #pragma unroll
    for (int i = 1; i < 8; ++i) m = fmaxf(m, v[i]);
    #pragma unroll
    for (int o = 32; o; o >>= 1) m = fmaxf(m, __shfl_xor(m, o, 64));
    if ((tid & 63) == 0) red[tid >> 6] = m;
    __syncthreads();
    m = fmaxf(fmaxf(red[0], red[1]), fmaxf(red[2], red[3]));

    float t[8];
    float s = 0.f;
    #pragma unroll
    for (int i = 0; i < 8; ++i) { t[i] = v[i] - m; v[i] = expf(t[i]); s += v[i]; }
    #pragma unroll
    for (int o = 32; o; o >>= 1) s += __shfl_xor(s, o, 64);
    __syncthreads();
    if ((tid & 63) == 0) red[tid >> 6] = s;
    __syncthreads();
    s = red[0] + red[1] + red[2] + red[3];

    const float inv = 1.0f / s;
    const float lns = logf(s);
    float e = 0.f;
    float pv[8];
    #pragma unroll
    for (int i = 0; i < 8; ++i) {
        pv[i] = v[i] * inv;
        e = fmaf(pv[i], t[i] - lns, e);
    }
    *(float4*)(p + base)     = make_float4(pv[0], pv[1], pv[2], pv[3]);
    *(float4*)(p + base + 4) = make_float4(pv[4], pv[5], pv[6], pv[7]);
    half8 h;
    #pragma unroll
    for (int i = 0; i < 8; ++i) h[i] = (_Float16)pv[i];
    *(half8*)(ph + base) = h;

    #pragma unroll
    for (int o = 32; o; o >>= 1) e += __shfl_xor(e, o, 64);
    __syncthreads();
    if ((tid & 63) == 0) red[tid >> 6] = e;
    __syncthreads();
    if (tid == 0) partials[row] = red[0] + red[1] + red[2] + red[3];
}

__global__ __launch_bounds__(256) void ent_reduce_kernel(
    const float* __restrict__ partials, float* __restrict__ ent)
{
    __shared__ float red[4];
    float s = 0.f;
    for (int i = threadIdx.x; i < BB * NN; i += 256) s += partials[i];
    #pragma unroll
    for (int o = 32; o; o >>= 1) s += __shfl_xor(s, o, 64);
    if ((threadIdx.x & 63) == 0) red[threadIdx.x >> 6] = s;
    __syncthreads();
    if (threadIdx.x == 0)
        *ent = -(red[0] + red[1] + red[2] + red[3]) / (float)(BB * NN);
}

extern "C" void kernel_launch(void* const* d_in, const int* in_sizes, int n_in,
                              void* d_out, int out_size, void* d_ws, size_t ws_size,
                              hipStream_t stream) {
    const float* query = (const float*)d_in[0];
    const float* key   = (const float*)d_in[1];
    const float* value = (const float*)d_in[2];
    const float* Wq    = (const float*)d_in[3];
    const float* Wk    = (const float*)d_in[4];
    const float* Wv    = (const float*)d_in[5];
    const float* si    = (const float*)d_in[6];

    float* out  = (float*)d_out;                        // [B,N,D]
    float* attn = out + (size_t)BB * NN * DD;           // [B,N,N]
    float* ent  = attn + (size_t)BB * NN * NN;          // scalar

    const size_t NK = (size_t)BB * NN * DD;             // 8.39M elements
    _Float16* ws16 = (_Float16*)d_ws;
    _Float16* qh = ws16;            // 16.8 MB each
    _Float16* ql = qh + NK;
    _Float16* kh = ql + NK;
    _Float16* kl = kh + NK;
    _Float16* vT = kl + NK;         // vT fp16 [b][512][2048]
    _Float16* WqhT = vT + NK;       // 0.5 MB each
    _Float16* WqlT = WqhT + DD * DD;
    _Float16* WkhT = WqlT + DD * DD;
    _Float16* WklT = WkhT + DD * DD;
    _Float16* WvhT = WklT + DD * DD;
    float* partials = (float*)(WvhT + DD * DD);         // 64 KB
    _Float16* attn_h = ws16;        // 67 MB, aliases qh..kl (dead after scores)

    const dim3 blk(256);
    const float inv_sqrt_d = 0.044194173824159216f;     // 1/sqrt(512)

    wsplit_kernel<<<dim3(8, 8, 3), blk, 0, stream>>>(Wq, Wk, Wv,
        WqhT, WqlT, WkhT, WklT, WvhT);

    // merged q/k projections (z = 0: query, z = 1: key), 3-product
    projqk_kernel<<<dim3(4, 128, 2), blk, 0, stream>>>(
        query, key, WqhT, WqlT, WkhT, WklT, qh, ql, kh, kl);
    // v projection, 1-product, writes vT fp16
    mm_nt<1><<<dim3(4, 128, 1), blk, 0, stream>>>(
        value, nullptr, WvhT, nullptr, vT, DD, DD, 0, 0, 0);

    // scores = q k^T / sqrt(d) + diag(min(exp(si),3))  [256^2 v4 pipeline]
    scores256_kernel<<<dim3(8, 8, 8), dim3(512), 131072, stream>>>(
        qh, ql, kh, kl, attn, si, inv_sqrt_d);

    softmax_entropy_kernel<<<dim3(BB * NN), blk, 0, stream>>>(attn, attn_h, partials);
    ent_reduce_kernel<<<dim3(1), blk, 0, stream>>>(partials, ent);

    // out = attn @ v : A = attn fp16 [2048][2048], B = vT fp16 [512][2048]
    mm_nt<3><<<dim3(4, 16, BB), blk, 0, stream>>>(
        nullptr, attn_h, vT, out, nullptr, DD, NN,
        (long)NN * NN, (long)DD * NN, (long)NN * DD);
}

// Round 8
// 334.958 us; speedup vs baseline: 1.0053x; 1.0023x over previous
//
#include <hip/hip_runtime.h>
#include <math.h>

#define BB 8
#define NN 2048
#define DD 512

typedef _Float16 halfT;
typedef _Float16 half8 __attribute__((ext_vector_type(8)));
typedef _Float16 half4 __attribute__((ext_vector_type(4)));
typedef float f32x4 __attribute__((ext_vector_type(4)));
typedef float f32x16 __attribute__((ext_vector_type(16)));

#define GLOAD16(gp, sp) __builtin_amdgcn_global_load_lds( \
    (const __attribute__((address_space(1))) void*)(gp), \
    (__attribute__((address_space(3))) void*)(sp), 16, 0, 0)

// ---------------------------------------------------------------------------
// W transpose + fp16 split:  WT[e][d] = W[d][e]  ->  (hi, lo) fp16 pairs
// ---------------------------------------------------------------------------
__global__ __launch_bounds__(256) void wsplit_kernel(
    const float* __restrict__ Wq, const float* __restrict__ Wk, const float* __restrict__ Wv,
    _Float16* __restrict__ qhT, _Float16* __restrict__ qlT,
    _Float16* __restrict__ khT, _Float16* __restrict__ klT,
    _Float16* __restrict__ vhT)
{
    __shared__ float t[64][65];
    const int z = blockIdx.z;
    const float* W = (z == 0) ? Wq : ((z == 1) ? Wk : Wv);
    _Float16* Ph = (z == 0) ? qhT : ((z == 1) ? khT : vhT);
    _Float16* Pl = (z == 0) ? qlT : ((z == 1) ? klT : nullptr);
    const int bx = blockIdx.x * 64, by = blockIdx.y * 64;
    const int tid = threadIdx.x;
    #pragma unroll
    for (int i = 0; i < 16; ++i) {
        const int idx = i * 256 + tid;
        const int r = idx >> 6, c = idx & 63;
        t[r][c] = W[(long)(by + r) * 512 + bx + c];
    }
    __syncthreads();
    #pragma unroll
    for (int i = 0; i < 16; ++i) {
        const int idx = i * 256 + tid;
        const int r = idx >> 6, c = idx & 63;
        const float v = t[c][r];
        const _Float16 h = (_Float16)v;
        const long o = (long)(bx + r) * 512 + by + c;
        Ph[o] = h;
        if (z < 2) Pl[o] = (_Float16)(v - (float)h);
    }
}

// ---------------------------------------------------------------------------
// Merged q/k projection: [16384,512] @ WT^T, 3-product fp16 split, 128x128
// tile, BK=32. blockIdx.z selects (query,Wq)->q or (key,Wk)->k.
// ---------------------------------------------------------------------------
__global__ __launch_bounds__(256) void projqk_kernel(
    const float* __restrict__ Af0, const float* __restrict__ Af1,
    const _Float16* __restrict__ B0h, const _Float16* __restrict__ B0l,
    const _Float16* __restrict__ B1h, const _Float16* __restrict__ B1l,
    _Float16* __restrict__ O0h, _Float16* __restrict__ O0l,
    _Float16* __restrict__ O1h, _Float16* __restrict__ O1l)
{
    __shared__ __align__(16) _Float16 smem[4 * 128 * 32];
    _Float16* Ah = smem;
    _Float16* Bh = smem + 4096;
    _Float16* Al = smem + 8192;
    _Float16* Bl = smem + 12288;

    const int z = blockIdx.z;
    const float* Af = z ? Af1 : Af0;
    const _Float16* Bgh = z ? B1h : B0h;
    const _Float16* Bgl = z ? B1l : B0l;
    _Float16* Oh = z ? O1h : O0h;
    _Float16* Ol = z ? O1l : O0l;

    const int tid  = threadIdx.x;
    const int lane = tid & 63;
    const int w    = tid >> 6;
    const int wr   = w >> 1, wc = w & 1;
    const int bm   = blockIdx.y * 128, bn = blockIdx.x * 128;

    f32x4 acc[4][4];
    #pragma unroll
    for (int i = 0; i < 4; ++i)
        #pragma unroll
        for (int j = 0; j < 4; ++j) acc[i][j] = (f32x4)0.0f;

    for (int k0 = 0; k0 < DD; k0 += 32) {
        #pragma unroll
        for (int i = 0; i < 2; ++i) {
            const int c   = i * 256 + w * 64 + lane;
            const int row = c >> 2, sl = c & 3;
            const long g  = (long)(bn + row) * DD + k0 + sl * 8;
            const int lb  = (i * 256 + w * 64) * 8;
            GLOAD16(Bgh + g, Bh + lb);
            GLOAD16(Bgl + g, Bl + lb);
        }
        #pragma unroll
        for (int i = 0; i < 4; ++i) {
            const int c = tid + i * 256;
            const int row = c >> 3, q4 = c & 7;
            const float4 v = *(const float4*)(Af + (long)(bm + row) * DD + k0 + q4 * 4);
            half4 h;
            h[0] = (_Float16)v.x; h[1] = (_Float16)v.y;
            h[2] = (_Float16)v.z; h[3] = (_Float16)v.w;
            *(half4*)&Ah[row * 32 + q4 * 4] = h;
            half4 l;
            l[0] = (_Float16)(v.x - (float)h[0]);
            l[1] = (_Float16)(v.y - (float)h[1]);
            l[2] = (_Float16)(v.z - (float)h[2]);
            l[3] = (_Float16)(v.w - (float)h[3]);
            *(half4*)&Al[row * 32 + q4 * 4] = l;
        }
        __syncthreads();

        half8 ah[4], bh[4], al[4], bl[4];
        #pragma unroll
        for (int f = 0; f < 4; ++f) {
            const int ar = wr * 64 + f * 16 + (lane & 15);
            const int ao = ar * 32 + ((lane >> 4) << 3);
            ah[f] = *(const half8*)&Ah[ao];
            al[f] = *(const half8*)&Al[ao];
            const int br = wc * 64 + f * 16 + (lane & 15);
            const int bo = br * 32 + ((lane >> 4) << 3);
            bh[f] = *(const half8*)&Bh[bo];
            bl[f] = *(const half8*)&Bl[bo];
        }
        #pragma unroll
        for (int i = 0; i < 4; ++i)
            #pragma unroll
            for (int j = 0; j < 4; ++j) {
                acc[i][j] = __builtin_amdgcn_mfma_f32_16x16x32_f16(ah[i], bh[j], acc[i][j], 0, 0, 0);
                acc[i][j] = __builtin_amdgcn_mfma_f32_16x16x32_f16(ah[i], bl[j], acc[i][j], 0, 0, 0);
                acc[i][j] = __builtin_amdgcn_mfma_f32_16x16x32_f16(al[i], bh[j], acc[i][j], 0, 0, 0);
            }
        __syncthreads();
    }

    #pragma unroll
    for (int i = 0; i < 4; ++i) {
        const int rb = bm + wr * 64 + i * 16 + ((lane >> 4) << 2);
        #pragma unroll
        for (int j = 0; j < 4; ++j) {
            const int gc = bn + wc * 64 + j * 16 + (lane & 15);
            #pragma unroll
            for (int r = 0; r < 4; ++r) {
                const float vv = acc[i][j][r];
                const _Float16 h = (_Float16)vv;
                const long o = (long)(rb + r) * DD + gc;
                Oh[o] = h;
                Ol[o] = (_Float16)(vv - (float)h);
            }
        }
    }
}

// ---------------------------------------------------------------------------
// v projection (m97-style 128x128): value fp32 -> vT fp16 [b][512][2048]
// ---------------------------------------------------------------------------
__global__ __launch_bounds__(256) void vproj_kernel(
    const float* __restrict__ Af, const _Float16* __restrict__ Bgh,
    _Float16* __restrict__ Oh)
{
    __shared__ __align__(16) _Float16 smem[2 * 128 * 32];
    _Float16* Ah = smem;
    _Float16* Bh = smem + 4096;

    const int tid  = threadIdx.x;
    const int lane = tid & 63;
    const int w    = tid >> 6;
    const int wr   = w >> 1, wc = w & 1;
    const int bm   = blockIdx.y * 128, bn = blockIdx.x * 128;

    f32x4 acc[4][4];
    #pragma unroll
    for (int i = 0; i < 4; ++i)
        #pragma unroll
        for (int j = 0; j < 4; ++j) acc[i][j] = (f32x4)0.0f;

    for (int k0 = 0; k0 < DD; k0 += 32) {
        #pragma unroll
        for (int i = 0; i < 2; ++i) {
            const int c   = i * 256 + w * 64 + lane;
            const int row = c >> 2, sl = c & 3;
            const long g  = (long)(bn + row) * DD + k0 + sl * 8;
            const int lb  = (i * 256 + w * 64) * 8;
            GLOAD16(Bgh + g, Bh + lb);
        }
        #pragma unroll
        for (int i = 0; i < 4; ++i) {
            const int c = tid + i * 256;
            const int row = c >> 3, q4 = c & 7;
            const float4 v = *(const float4*)(Af + (long)(bm + row) * DD + k0 + q4 * 4);
            half4 h;
            h[0] = (_Float16)v.x; h[1] = (_Float16)v.y;
            h[2] = (_Float16)v.z; h[3] = (_Float16)v.w;
            *(half4*)&Ah[row * 32 + q4 * 4] = h;
        }
        __syncthreads();

        half8 ah[4], bh[4];
        #pragma unroll
        for (int f = 0; f < 4; ++f) {
            const int ar = wr * 64 + f * 16 + (lane & 15);
            ah[f] = *(const half8*)&Ah[ar * 32 + ((lane >> 4) << 3)];
            const int br = wc * 64 + f * 16 + (lane & 15);
            bh[f] = *(const half8*)&Bh[br * 32 + ((lane >> 4) << 3)];
        }
        #pragma unroll
        for (int i = 0; i < 4; ++i)
            #pragma unroll
            for (int j = 0; j < 4; ++j)
                acc[i][j] = __builtin_amdgcn_mfma_f32_16x16x32_f16(ah[i], bh[j], acc[i][j], 0, 0, 0);
        __syncthreads();
    }

    #pragma unroll
    for (int i = 0; i < 4; ++i) {
        const int rb = bm + wr * 64 + i * 16 + ((lane >> 4) << 2);
        #pragma unroll
        for (int j = 0; j < 4; ++j) {
            const int gc = bn + wc * 64 + j * 16 + (lane & 15);
            half4 hv;
            #pragma unroll
            for (int r = 0; r < 4; ++r) hv[r] = (_Float16)acc[i][j][r];
            const int b = rb >> 11, rIn = rb & 2047;
            *(half4*)&Oh[((long)b * 512 + gc) * 2048 + rIn] = hv;
        }
    }
}

// ---------------------------------------------------------------------------
// scores256 v5: v2 skeleton (2-phase dbuf gload_lds, pre-swizzled source,
// conflict-free) but with mfma_f32_32x32x16_f16 (+15% rate, half the
// instructions). Per wave: 128x64 out = 4m x 2n frags of 32x32, acc 8xf32x16.
// ---------------------------------------------------------------------------
__global__ __launch_bounds__(512, 2) void scores256_kernel(
    const halfT* __restrict__ qh, const halfT* __restrict__ ql,
    const halfT* __restrict__ kh, const halfT* __restrict__ kl,
    float* __restrict__ C, const float* __restrict__ si, float scale)
{
    extern __shared__ __align__(16) char smem[];   // 2 bufs x 65536 B
    // buf layout (byte offsets): Ah 0 | Al 16384 | Bh 32768 | Bl 49152

    const int tid  = threadIdx.x;
    const int lane = tid & 63;
    const int w    = tid >> 6;
    const int wr   = w >> 2, wc = w & 3;  // per-wave output 128 x 64

    int flat = (blockIdx.z << 6) | (blockIdx.y << 3) | blockIdx.x;
    flat = ((flat & 7) << 6) | (flat >> 3);
    const int bx = flat & 7, by = (flat >> 3) & 7, bz = flat >> 6;
    const int bm = by * 256, bn = bx * 256;

    const long zoff = (long)bz * NN * DD;
    const halfT* A_h = qh + zoff;
    const halfT* A_l = ql + zoff;
    const halfT* B_h = kh + zoff;
    const halfT* B_l = kl + zoff;

    const int s_row   = w * 16 + (lane >> 2);
    const int s_chunk = (lane & 3) ^ ((lane >> 3) & 3);
    const long gA = (long)(bm + s_row) * DD + s_chunk * 8;
    const long gB = (long)(bn + s_row) * DD + s_chunk * 8;
    const int ldst = w * 1024;
    const long rstep = (long)128 * DD;

    auto stage = [&](char* buf, int t) {
        const long kk = (long)t * 32;
        GLOAD16(A_h + gA + kk,         buf + ldst);
        GLOAD16(A_h + gA + rstep + kk, buf + 8192 + ldst);
        GLOAD16(A_l + gA + kk,         buf + 16384 + ldst);
        GLOAD16(A_l + gA + rstep + kk, buf + 16384 + 8192 + ldst);
        GLOAD16(B_h + gB + kk,         buf + 32768 + ldst);
        GLOAD16(B_h + gB + rstep + kk, buf + 32768 + 8192 + ldst);
        GLOAD16(B_l + gB + kk,         buf + 49152 + ldst);
        GLOAD16(B_l + gB + rstep + kk, buf + 49152 + 8192 + ldst);
    };

    // 32x32 fragment read: lane holds row = sub + (lane&31), k-granule
    // g = kh*2 + (lane>>5); phys granule = g ^ ((row>>1)&3).
    const int frow = lane & 31;
    const int fgr  = lane >> 5;

    f32x16 acc[4][2];
    #pragma unroll
    for (int m = 0; m < 4; ++m)
        #pragma unroll
        for (int n = 0; n < 2; ++n) acc[m][n] = (f32x16)0.0f;

    stage(smem, 0);
    asm volatile("s_waitcnt vmcnt(0)" ::: "memory");
    __builtin_amdgcn_s_barrier();
    __builtin_amdgcn_sched_barrier(0);

    for (int t = 0; t < 16; ++t) {
        char* cur = smem + (size_t)(t & 1) * 65536;
        char* nxt = smem + (size_t)((t + 1) & 1) * 65536;

        if (t < 15) stage(nxt, t + 1);

        auto fr = [&](const char* unit, int row, int kh) -> half8 {
            const int g = kh * 2 + fgr;
            const int phys = g ^ ((row >> 1) & 3);
            return *(const half8*)(unit + row * 64 + phys * 16);
        };

        half8 a_[4][2], bh_[2][2];
        #pragma unroll
        for (int kh2 = 0; kh2 < 2; ++kh2) {
            #pragma unroll
            for (int n = 0; n < 2; ++n)
                bh_[n][kh2] = fr(cur + 32768, wc * 64 + n * 32 + frow, kh2);
            #pragma unroll
            for (int m = 0; m < 4; ++m)
                a_[m][kh2] = fr(cur, wr * 128 + m * 32 + frow, kh2);
        }
        __builtin_amdgcn_s_setprio(1);
        #pragma unroll
        for (int m = 0; m < 4; ++m)
            #pragma unroll
            for (int n = 0; n < 2; ++n)
                #pragma unroll
                for (int kh2 = 0; kh2 < 2; ++kh2)
                    acc[m][n] = __builtin_amdgcn_mfma_f32_32x32x16_f16(a_[m][kh2], bh_[n][kh2], acc[m][n], 0, 0, 0);
        __builtin_amdgcn_s_setprio(0);

        half8 bl_[2][2];
        #pragma unroll
        for (int kh2 = 0; kh2 < 2; ++kh2)
            #pragma unroll
            for (int n = 0; n < 2; ++n)
                bl_[n][kh2] = fr(cur + 49152, wc * 64 + n * 32 + frow, kh2);
        __builtin_amdgcn_s_setprio(1);
        #pragma unroll
        for (int m = 0; m < 4; ++m)
            #pragma unroll
            for (int n = 0; n < 2; ++n)
                #pragma unroll
                for (int kh2 = 0; kh2 < 2; ++kh2)
                    acc[m][n] = __builtin_amdgcn_mfma_f32_32x32x16_f16(a_[m][kh2], bl_[n][kh2], acc[m][n], 0, 0, 0);
        __builtin_amdgcn_s_setprio(0);

        __builtin_amdgcn_s_setprio(1);
        #pragma unroll
        for (int m = 0; m < 4; ++m) {
            half8 al0 = fr(cur + 16384, wr * 128 + m * 32 + frow, 0);
            half8 al1 = fr(cur + 16384, wr * 128 + m * 32 + frow, 1);
            #pragma unroll
            for (int n = 0; n < 2; ++n) {
                acc[m][n] = __builtin_amdgcn_mfma_f32_32x32x16_f16(al0, bh_[n][0], acc[m][n], 0, 0, 0);
                acc[m][n] = __builtin_amdgcn_mfma_f32_32x32x16_f16(al1, bh_[n][1], acc[m][n], 0, 0, 0);
            }
        }
        __builtin_amdgcn_s_setprio(0);

        if (t < 15) {
            asm volatile("s_waitcnt vmcnt(0)" ::: "memory");
            __builtin_amdgcn_s_barrier();
        }
    }

    // epilogue: 32x32 C layout: row=(reg&3)+8*(reg>>2)+4*(lane>>5), col=lane&31
    float* Cz = C + (long)bz * NN * NN;
    const int rbias = 4 * (lane >> 5);
    #pragma unroll
    for (int m = 0; m < 4; ++m) {
        #pragma unroll
        for (int n = 0; n < 2; ++n) {
            const int gc = bn + wc * 64 + n * 32 + (lane & 31);
            #pragma unroll
            for (int reg = 0; reg < 16; ++reg) {
                const int gr = bm + wr * 128 + m * 32 + (reg & 3) + 8 * (reg >> 2) + rbias;
                float vv = acc[m][n][reg] * scale;
                if (gr == gc) vv += fminf(expf(si[gr]), 3.0f);
                Cz[(long)gr * NN + gc] = vv;
            }
        }
    }
}

// ---------------------------------------------------------------------------
// AV GEMM: out[b] = attn_h[b] @ vT[b]^T.  256M x 128N tile, 8 waves (2m x 4n,
// per-wave 128x32), K=2048 (64 tiles of 32), single fp16 product, 32x32 MFMA,
// gload_lds dbuf + pre-swizzled source (conflict-free). Grid 256 = 1/CU.
// ---------------------------------------------------------------------------
__global__ __launch_bounds__(512, 2) void av_kernel(
    const halfT* __restrict__ P, const halfT* __restrict__ V,
    float* __restrict__ O)
{
    extern __shared__ __align__(16) char smem[];   // 2 bufs x 24576 B
    // buf layout: A 0 (16 KB, 256 rows) | B 16384 (8 KB, 128 rows)

    const int tid  = threadIdx.x;
    const int lane = tid & 63;
    const int w    = tid >> 6;
    const int wr   = w >> 2, wc = w & 3;  // per-wave 128 x 32

    int flat = (blockIdx.z << 5) | (blockIdx.y << 2) | blockIdx.x;
    flat = ((flat & 7) << 5) | (flat >> 3);
    const int nx = flat & 3, my = (flat >> 2) & 7, bz = flat >> 5;
    const int bm = my * 256, bn = nx * 128;

    const halfT* A = P + (long)bz * NN * NN;
    const halfT* B = V + (long)bz * DD * NN;

    const int s_row   = w * 16 + (lane >> 2);
    const int s_chunk = (lane & 3) ^ ((lane >> 3) & 3);
    const long gA = (long)(bm + s_row) * NN + s_chunk * 8;
    const long gB = (long)(bn + s_row) * NN + s_chunk * 8;
    const int ldst = w * 1024;
    const long rstep = (long)128 * NN;

    auto stage = [&](char* buf, int t) {
        const long kk = (long)t * 32;
        GLOAD16(A + gA + kk,         buf + ldst);
        GLOAD16(A + gA + rstep + kk, buf + 8192 + ldst);
        GLOAD16(B + gB + kk,         buf + 16384 + ldst);
    };

    const int frow = lane & 31;
    const int fgr  = lane >> 5;

    f32x16 acc[4];
    #pragma unroll
    for (int m = 0; m < 4; ++m) acc[m] = (f32x16)0.0f;

    stage(smem, 0);
    asm volatile("s_waitcnt vmcnt(0)" ::: "memory");
    __builtin_amdgcn_s_barrier();
    __builtin_amdgcn_sched_barrier(0);

    for (int t = 0; t < 64; ++t) {
        char* cur = smem + (size_t)(t & 1) * 24576;
        char* nxt = smem + (size_t)((t + 1) & 1) * 24576;

        if (t < 63) stage(nxt, t + 1);

        auto fr = [&](const char* unit, int row, int kh) -> half8 {
            const int g = kh * 2 + fgr;
            const int phys = g ^ ((row >> 1) & 3);
            return *(const half8*)(unit + row * 64 + phys * 16);
        };

        half8 a_[4][2], b_[2];
        #pragma unroll
        for (int kh2 = 0; kh2 < 2; ++kh2) {
            b_[kh2] = fr(cur + 16384, wc * 32 + frow, kh2);
            #pragma unroll
            for (int m = 0; m < 4; ++m)
                a_[m][kh2] = fr(cur, wr * 128 + m * 32 + frow, kh2);
        }
        __builtin_amdgcn_s_setprio(1);
        #pragma unroll
        for (int m = 0; m < 4; ++m)
            #pragma unroll
            for (int kh2 = 0; kh2 < 2; ++kh2)
                acc[m] = __builtin_amdgcn_mfma_f32_32x32x16_f16(a_[m][kh2], b_[kh2], acc[m], 0, 0, 0);
        __builtin_amdgcn_s_setprio(0);

        if (t < 63) {
            asm volatile("s_waitcnt vmcnt(0)" ::: "memory");
            __builtin_amdgcn_s_barrier();
        }
    }

    float* Oz = O + (long)bz * NN * DD;
    const int rbias = 4 * (lane >> 5);
    const int gc = bn + wc * 32 + (lane & 31);
    #pragma unroll
    for (int m = 0; m < 4; ++m) {
        #pragma unroll
        for (int reg = 0; reg < 16; ++reg) {
            const int gr = bm + wr * 128 + m * 32 + (reg & 3) + 8 * (reg >> 2) + rbias;
            Oz[(long)gr * DD + gc] = acc[m][reg];
        }
    }
}

// ---------------------------------------------------------------------------
// In-place row softmax + entropy partial + fp16 copy of attn.
// ---------------------------------------------------------------------------
__global__ __launch_bounds__(256) void softmax_entropy_kernel(
    float* __restrict__ attn, _Float16* __restrict__ ah, float* __restrict__ partials)
{
    __shared__ float red[4];
    const long row = blockIdx.x;
    float* p = attn + row * (long)NN;
    _Float16* ph = ah + row * (long)NN;
    const int tid = threadIdx.x;
    const int base = tid * 8;

    float4 va = *(const float4*)(p + base);
    float4 vb = *(const float4*)(p + base + 4);
    float v[8] = {va.x, va.y, va.z, va.w, vb.x, vb.y, vb.z, vb.w};

    float m = v[0];
    #pragma unroll
    for (int i = 1; i < 8; ++i) m = fmaxf(m, v[i]);
    #pragma unroll
    for (int o = 32; o; o >>= 1) m = fmaxf(m, __shfl_xor(m, o, 64));
    if ((tid & 63) == 0) red[tid >> 6] = m;
    __syncthreads();
    m = fmaxf(fmaxf(red[0], red[1]), fmaxf(red[2], red[3]));

    float t[8];
    float s = 0.f;
    #pragma unroll
    for (int i = 0; i < 8; ++i) { t[i] = v[i] - m; v[i] = expf(t[i]); s += v[i]; }
    #pragma unroll
    for (int o = 32; o; o >>= 1) s += __shfl_xor(s, o, 64);
    __syncthreads();
    if ((tid & 63) == 0) red[tid >> 6] = s;
    __syncthreads();
    s = red[0] + red[1] + red[2] + red[3];

    const float inv = 1.0f / s;
    const float lns = logf(s);
    float e = 0.f;
    float pv[8];
    #pragma unroll
    for (int i = 0; i < 8; ++i) {
        pv[i] = v[i] * inv;
        e = fmaf(pv[i], t[i] - lns, e);
    }
    *(float4*)(p + base)     = make_float4(pv[0], pv[1], pv[2], pv[3]);
    *(float4*)(p + base + 4) = make_float4(pv[4], pv[5], pv[6], pv[7]);
    half8 h;
    #pragma unroll
    for (int i = 0; i < 8; ++i) h[i] = (_Float16)pv[i];
    *(half8*)(ph + base) = h;

    #pragma unroll
    for (int o = 32; o; o >>= 1) e += __shfl_xor(e, o, 64);
    __syncthreads();
    if ((tid & 63) == 0) red[tid >> 6] = e;
    __syncthreads();
    if (tid == 0) partials[row] = red[0] + red[1] + red[2] + red[3];
}

__global__ __launch_bounds__(256) void ent_reduce_kernel(
    const float* __restrict__ partials, float* __restrict__ ent)
{
    __shared__ float red[4];
    float s = 0.f;
    for (int i = threadIdx.x; i < BB * NN; i += 256) s += partials[i];
    #pragma unroll
    for (int o = 32; o; o >>= 1) s += __shfl_xor(s, o, 64);
    if ((threadIdx.x & 63) == 0) red[threadIdx.x >> 6] = s;
    __syncthreads();
    if (threadIdx.x == 0)
        *ent = -(red[0] + red[1] + red[2] + red[3]) / (float)(BB * NN);
}

extern "C" void kernel_launch(void* const* d_in, const int* in_sizes, int n_in,
                              void* d_out, int out_size, void* d_ws, size_t ws_size,
                              hipStream_t stream) {
    const float* query = (const float*)d_in[0];
    const float* key   = (const float*)d_in[1];
    const float* value = (const float*)d_in[2];
    const float* Wq    = (const float*)d_in[3];
    const float* Wk    = (const float*)d_in[4];
    const float* Wv    = (const float*)d_in[5];
    const float* si    = (const float*)d_in[6];

    float* out  = (float*)d_out;                        // [B,N,D]
    float* attn = out + (size_t)BB * NN * DD;           // [B,N,N]
    float* ent  = attn + (size_t)BB * NN * NN;          // scalar

    const size_t NK = (size_t)BB * NN * DD;             // 8.39M elements
    _Float16* ws16 = (_Float16*)d_ws;
    _Float16* qh = ws16;            // 16.8 MB each
    _Float16* ql = qh + NK;
    _Float16* kh = ql + NK;
    _Float16* kl = kh + NK;
    _Float16* vT = kl + NK;         // vT fp16 [b][512][2048]
    _Float16* WqhT = vT + NK;       // 0.5 MB each
    _Float16* WqlT = WqhT + DD * DD;
    _Float16* WkhT = WqlT + DD * DD;
    _Float16* WklT = WkhT + DD * DD;
    _Float16* WvhT = WklT + DD * DD;
    float* partials = (float*)(WvhT + DD * DD);         // 64 KB
    _Float16* attn_h = ws16;        // 67 MB, aliases qh..kl (dead after scores)

    const dim3 blk(256);
    const float inv_sqrt_d = 0.044194173824159216f;     // 1/sqrt(512)

    wsplit_kernel<<<dim3(8, 8, 3), blk, 0, stream>>>(Wq, Wk, Wv,
        WqhT, WqlT, WkhT, WklT, WvhT);

    // merged q/k projections (z = 0: query, z = 1: key), 3-product
    projqk_kernel<<<dim3(4, 128, 2), blk, 0, stream>>>(
        query, key, WqhT, WqlT, WkhT, WklT, qh, ql, kh, kl);
    // v projection, 1-product, writes vT fp16
    vproj_kernel<<<dim3(4, 128, 1), blk, 0, stream>>>(value, WvhT, vT);

    // scores = q k^T / sqrt(d) + diag(min(exp(si),3))  [v5: 32x32 MFMA]
    scores256_kernel<<<dim3(8, 8, 8), dim3(512), 131072, stream>>>(
        qh, ql, kh, kl, attn, si, inv_sqrt_d);

    softmax_entropy_kernel<<<dim3(BB * NN), blk, 0, stream>>>(attn, attn_h, partials);
    ent_reduce_kernel<<<dim3(1), blk, 0, stream>>>(partials, ent);

    // out = attn @ v  [new 256x128-tile 32x32-MFMA pipeline]
    av_kernel<<<dim3(4, 8, 8), dim3(512), 49152, stream>>>(attn_h, vT, out);
}

// Round 9
// 314.395 us; speedup vs baseline: 1.0710x; 1.0654x over previous
//
#include <hip/hip_runtime.h>
#include <math.h>

#define BB 8
#define NN 2048
#define DD 512

typedef _Float16 halfT;
typedef _Float16 half8 __attribute__((ext_vector_type(8)));
typedef _Float16 half4 __attribute__((ext_vector_type(4)));
typedef float f32x4 __attribute__((ext_vector_type(4)));

#define GLOAD16(gp, sp) __builtin_amdgcn_global_load_lds( \
    (const __attribute__((address_space(1))) void*)(gp), \
    (__attribute__((address_space(3))) void*)(sp), 16, 0, 0)

// ---------------------------------------------------------------------------
// W transpose + fp16 split:  WT[e][d] = W[d][e]  ->  (hi, lo) fp16 pairs
// ---------------------------------------------------------------------------
__global__ __launch_bounds__(256) void wsplit_kernel(
    const float* __restrict__ Wq, const float* __restrict__ Wk, const float* __restrict__ Wv,
    _Float16* __restrict__ qhT, _Float16* __restrict__ qlT,
    _Float16* __restrict__ khT, _Float16* __restrict__ klT,
    _Float16* __restrict__ vhT)
{
    __shared__ float t[64][65];
    const int z = blockIdx.z;
    const float* W = (z == 0) ? Wq : ((z == 1) ? Wk : Wv);
    _Float16* Ph = (z == 0) ? qhT : ((z == 1) ? khT : vhT);
    _Float16* Pl = (z == 0) ? qlT : ((z == 1) ? klT : nullptr);
    const int bx = blockIdx.x * 64, by = blockIdx.y * 64;
    const int tid = threadIdx.x;
    #pragma unroll
    for (int i = 0; i < 16; ++i) {
        const int idx = i * 256 + tid;
        const int r = idx >> 6, c = idx & 63;
        t[r][c] = W[(long)(by + r) * 512 + bx + c];
    }
    __syncthreads();
    #pragma unroll
    for (int i = 0; i < 16; ++i) {
        const int idx = i * 256 + tid;
        const int r = idx >> 6, c = idx & 63;
        const float v = t[c][r];
        const _Float16 h = (_Float16)v;
        const long o = (long)(bx + r) * 512 + by + c;
        Ph[o] = h;
        if (z < 2) Pl[o] = (_Float16)(v - (float)h);
    }
}

// ---------------------------------------------------------------------------
// projqk v6: 256x128 tile, 8 waves (4wr x 2wc, 64x64 per wave), BK=32,
// 3-product fp16 split. B (pre-split WT) via gload_lds + pre-swizzled source;
// A (fp32 X) reg-staged (T14): load at step top, cvt+split+ds_write after the
// MFMA cluster. One vmcnt(0)+lgkmcnt(0)+barrier per K-step. z: 0=query 1=key.
// ---------------------------------------------------------------------------
__global__ __launch_bounds__(512, 2) void projqk_kernel(
    const float* __restrict__ X0, const float* __restrict__ X1,
    const halfT* __restrict__ B0h, const halfT* __restrict__ B0l,
    const halfT* __restrict__ B1h, const halfT* __restrict__ B1l,
    halfT* __restrict__ O0h, halfT* __restrict__ O0l,
    halfT* __restrict__ O1h, halfT* __restrict__ O1l)
{
    extern __shared__ __align__(16) char smem[];   // 2 bufs x 49152 B
    // buf layout: Ah 0 | Al 16384 | Bh 32768 | Bl 40960

    const int tid  = threadIdx.x;
    const int lane = tid & 63;
    const int w    = tid >> 6;
    const int wr   = w >> 1, wc = w & 1;   // wave = 64 rows x 64 cols

    // bijective XCD swizzle: 64-block slabs per XCD; nx-siblings co-located
    const int h = blockIdx.x;                    // 0..511
    const int L = ((h & 7) << 6) | (h >> 3);
    const int z  = L >> 8;
    const int nx = L & 3, my = (L >> 2) & 63;
    const int bm = my * 256, bn = nx * 128;

    const float* X = z ? X1 : X0;
    const halfT* Bgh = z ? B1h : B0h;
    const halfT* Bgl = z ? B1l : B0l;
    halfT* Oh = z ? O1h : O0h;
    halfT* Ol = z ? O1l : O0l;

    // ---- B staging (gload_lds, pre-swizzled source) ----
    const int b_row   = w * 16 + (lane >> 2);            // 0..127
    const int b_chunk = (lane & 3) ^ ((lane >> 3) & 3);  // = (lane&3)^((b_row>>1)&3)
    const long gB = (long)(bn + b_row) * DD + b_chunk * 8;
    const int ldstB = w * 1024;

    // ---- A reg staging: thread covers granules (a_row0, a_gc), (a_row0+128, a_gc)
    const int a_row0 = tid >> 2;           // 0..127
    const int a_gc   = tid & 3;
    const int a_phys = a_gc ^ ((a_row0 >> 1) & 3);   // same for row0+128 (128>>1 ≡ 0 mod 4)
    const long gA0 = (long)(bm + a_row0) * DD + a_gc * 8;
    const long gA1 = (long)(bm + a_row0 + 128) * DD + a_gc * 8;
    const int aOff0 = a_row0 * 64 + a_phys * 16;
    const int aOff1 = (a_row0 + 128) * 64 + a_phys * 16;

    float ar[16];
    auto loadA = [&](int t) {
        const long kk = (long)t * 32;
        *(float4*)&ar[0]  = *(const float4*)(X + gA0 + kk);
        *(float4*)&ar[4]  = *(const float4*)(X + gA0 + kk + 4);
        *(float4*)&ar[8]  = *(const float4*)(X + gA1 + kk);
        *(float4*)&ar[12] = *(const float4*)(X + gA1 + kk + 4);
    };
    auto stageB = [&](char* buf, int t) {
        const long kk = (long)t * 32;
        GLOAD16(Bgh + gB + kk, buf + 32768 + ldstB);
        GLOAD16(Bgl + gB + kk, buf + 40960 + ldstB);
    };
    auto writeA = [&](char* buf) {
        half8 h0, l0, h1, l1;
        #pragma unroll
        for (int i = 0; i < 8; ++i) {
            const _Float16 hh = (_Float16)ar[i];
            h0[i] = hh; l0[i] = (_Float16)(ar[i] - (float)hh);
        }
        #pragma unroll
        for (int i = 0; i < 8; ++i) {
            const _Float16 hh = (_Float16)ar[8 + i];
            h1[i] = hh; l1[i] = (_Float16)(ar[8 + i] - (float)hh);
        }
        *(half8*)(buf + aOff0)         = h0;
        *(half8*)(buf + 16384 + aOff0) = l0;
        *(half8*)(buf + aOff1)         = h1;
        *(half8*)(buf + 16384 + aOff1) = l1;
    };

    // fragment read offset (v2 involution, proven conflict-free)
    const int lr  = lane & 15;
    const int q16 = lane >> 4;
    const int frag = lr * 64 + ((q16 ^ ((lr >> 1) & 3)) << 4);
    const int abase = wr * 4096 + frag;   // A rows wr*64, + m*1024
    const int bbase = wc * 4096 + frag;   // B rows wc*64, + j*1024

    f32x4 acc[4][4];
    #pragma unroll
    for (int i = 0; i < 4; ++i)
        #pragma unroll
        for (int j = 0; j < 4; ++j) acc[i][j] = (f32x4)0.0f;

    // prologue
    loadA(0);
    stageB(smem, 0);
    writeA(smem);
    asm volatile("s_waitcnt vmcnt(0) lgkmcnt(0)" ::: "memory");
    __builtin_amdgcn_s_barrier();
    __builtin_amdgcn_sched_barrier(0);

    for (int t = 0; t < 16; ++t) {
        char* cur = smem + (size_t)(t & 1) * 49152;
        char* nxt = smem + (size_t)((t + 1) & 1) * 49152;
        const bool pf = (t < 15);

        if (pf) { loadA(t + 1); stageB(nxt, t + 1); }

        half8 ah[4], bh[4], bl[4];
        #pragma unroll
        for (int m = 0; m < 4; ++m)
            ah[m] = *(const half8*)(cur + abase + m * 1024);
        #pragma unroll
        for (int j = 0; j < 4; ++j)
            bh[j] = *(const half8*)(cur + 32768 + bbase + j * 1024);
        __builtin_amdgcn_s_setprio(1);
        #pragma unroll
        for (int m = 0; m < 4; ++m)
            #pragma unroll
            for (int j = 0; j < 4; ++j)
                acc[m][j] = __builtin_amdgcn_mfma_f32_16x16x32_f16(ah[m], bh[j], acc[m][j], 0, 0, 0);
        __builtin_amdgcn_s_setprio(0);

        #pragma unroll
        for (int j = 0; j < 4; ++j)
            bl[j] = *(const half8*)(cur + 40960 + bbase + j * 1024);
        __builtin_amdgcn_s_setprio(1);
        #pragma unroll
        for (int m = 0; m < 4; ++m)
            #pragma unroll
            for (int j = 0; j < 4; ++j)
                acc[m][j] = __builtin_amdgcn_mfma_f32_16x16x32_f16(ah[m], bl[j], acc[m][j], 0, 0, 0);
        __builtin_amdgcn_s_setprio(0);

        __builtin_amdgcn_s_setprio(1);
        #pragma unroll
        for (int m = 0; m < 4; ++m) {
            const half8 al = *(const half8*)(cur + 16384 + abase + m * 1024);
            #pragma unroll
            for (int j = 0; j < 4; ++j)
                acc[m][j] = __builtin_amdgcn_mfma_f32_16x16x32_f16(al, bh[j], acc[m][j], 0, 0, 0);
        }
        __builtin_amdgcn_s_setprio(0);

        if (pf) writeA(nxt);
        asm volatile("s_waitcnt vmcnt(0) lgkmcnt(0)" ::: "memory");
        __builtin_amdgcn_s_barrier();
        __builtin_amdgcn_sched_barrier(0);
    }

    // epilogue: fp16 split store
    #pragma unroll
    for (int m = 0; m < 4; ++m) {
        const int rb = bm + wr * 64 + m * 16 + (q16 << 2);
        #pragma unroll
        for (int j = 0; j < 4; ++j) {
            const int gc = bn + wc * 64 + j * 16 + lr;
            #pragma unroll
            for (int r = 0; r < 4; ++r) {
                const float vv = acc[m][j][r];
                const _Float16 hh = (_Float16)vv;
                const long o = (long)(rb + r) * DD + gc;
                Oh[o] = hh;
                Ol[o] = (_Float16)(vv - (float)hh);
            }
        }
    }
}

// ---------------------------------------------------------------------------
// v projection (m97-style 128x128): value fp32 -> vT fp16 [b][512][2048]
// ---------------------------------------------------------------------------
__global__ __launch_bounds__(256) void vproj_kernel(
    const float* __restrict__ Af, const _Float16* __restrict__ Bgh,
    _Float16* __restrict__ Oh)
{
    __shared__ __align__(16) _Float16 smem[2 * 128 * 32];
    _Float16* Ah = smem;
    _Float16* Bh = smem + 4096;

    const int tid  = threadIdx.x;
    const int lane = tid & 63;
    const int w    = tid >> 6;
    const int wr   = w >> 1, wc = w & 1;
    const int bm   = blockIdx.y * 128, bn = blockIdx.x * 128;

    f32x4 acc[4][4];
    #pragma unroll
    for (int i = 0; i < 4; ++i)
        #pragma unroll
        for (int j = 0; j < 4; ++j) acc[i][j] = (f32x4)0.0f;

    for (int k0 = 0; k0 < DD; k0 += 32) {
        #pragma unroll
        for (int i = 0; i < 2; ++i) {
            const int c   = i * 256 + w * 64 + lane;
            const int row = c >> 2, sl = c & 3;
            const long g  = (long)(bn + row) * DD + k0 + sl * 8;
            const int lb  = (i * 256 + w * 64) * 8;
            GLOAD16(Bgh + g, Bh + lb);
        }
        #pragma unroll
        for (int i = 0; i < 4; ++i) {
            const int c = tid + i * 256;
            const int row = c >> 3, q4 = c & 7;
            const float4 v = *(const float4*)(Af + (long)(bm + row) * DD + k0 + q4 * 4);
            half4 h;
            h[0] = (_Float16)v.x; h[1] = (_Float16)v.y;
            h[2] = (_Float16)v.z; h[3] = (_Float16)v.w;
            *(half4*)&Ah[row * 32 + q4 * 4] = h;
        }
        __syncthreads();

        half8 ah[4], bh[4];
        #pragma unroll
        for (int f = 0; f < 4; ++f) {
            const int arr = wr * 64 + f * 16 + (lane & 15);
            ah[f] = *(const half8*)&Ah[arr * 32 + ((lane >> 4) << 3)];
            const int brr = wc * 64 + f * 16 + (lane & 15);
            bh[f] = *(const half8*)&Bh[brr * 32 + ((lane >> 4) << 3)];
        }
        #pragma unroll
        for (int i = 0; i < 4; ++i)
            #pragma unroll
            for (int j = 0; j < 4; ++j)
                acc[i][j] = __builtin_amdgcn_mfma_f32_16x16x32_f16(ah[i], bh[j], acc[i][j], 0, 0, 0);
        __syncthreads();
    }

    #pragma unroll
    for (int i = 0; i < 4; ++i) {
        const int rb = bm + wr * 64 + i * 16 + ((lane >> 4) << 2);
        #pragma unroll
        for (int j = 0; j < 4; ++j) {
            const int gc = bn + wc * 64 + j * 16 + (lane & 15);
            half4 hv;
            #pragma unroll
            for (int r = 0; r < 4; ++r) hv[r] = (_Float16)acc[i][j][r];
            const int b = rb >> 11, rIn = rb & 2047;
            *(half4*)&Oh[((long)b * 512 + gc) * 2048 + rIn] = hv;
        }
    }
}

// ---------------------------------------------------------------------------
// scores256 v2 (proven 122us, 0 conflicts): 256x256 tile, 8 waves (2x4),
// BK=32, 3-product split, gload_lds dbuf with pre-swizzled source, 2-phase.
// ---------------------------------------------------------------------------
__global__ __launch_bounds__(512, 2) void scores256_kernel(
    const halfT* __restrict__ qh, const halfT* __restrict__ ql,
    const halfT* __restrict__ kh, const halfT* __restrict__ kl,
    float* __restrict__ C, const float* __restrict__ si, float scale)
{
    extern __shared__ __align__(16) char smem[];   // 2 bufs x 65536 B
    // buf layout: Ah 0 | Al 16384 | Bh 32768 | Bl 49152

    const int tid  = threadIdx.x;
    const int lane = tid & 63;
    const int w    = tid >> 6;
    const int wr   = w >> 2, wc = w & 3;  // per-wave output 128 x 64

    int flat = (blockIdx.z << 6) | (blockIdx.y << 3) | blockIdx.x;
    flat = ((flat & 7) << 6) | (flat >> 3);
    const int bx = flat & 7, by = (flat >> 3) & 7, bz = flat >> 6;
    const int bm = by * 256, bn = bx * 256;

    const long zoff = (long)bz * NN * DD;
    const halfT* A_h = qh + zoff;
    const halfT* A_l = ql + zoff;
    const halfT* B_h = kh + zoff;
    const halfT* B_l = kl + zoff;

    const int s_row   = w * 16 + (lane >> 2);
    const int s_chunk = (lane & 3) ^ ((lane >> 3) & 3);
    const long gA = (long)(bm + s_row) * DD + s_chunk * 8;
    const long gB = (long)(bn + s_row) * DD + s_chunk * 8;
    const int ldst = w * 1024;
    const long rstep = (long)128 * DD;

    auto stage = [&](char* buf, int t) {
        const long kk = (long)t * 32;
        GLOAD16(A_h + gA + kk,         buf + ldst);
        GLOAD16(A_h + gA + rstep + kk, buf + 8192 + ldst);
        GLOAD16(A_l + gA + kk,         buf + 16384 + ldst);
        GLOAD16(A_l + gA + rstep + kk, buf + 16384 + 8192 + ldst);
        GLOAD16(B_h + gB + kk,         buf + 32768 + ldst);
        GLOAD16(B_h + gB + rstep + kk, buf + 32768 + 8192 + ldst);
        GLOAD16(B_l + gB + kk,         buf + 49152 + ldst);
        GLOAD16(B_l + gB + rstep + kk, buf + 49152 + 8192 + ldst);
    };

    const int lr   = lane & 15;
    const int q16  = lane >> 4;
    const int fswz = (lr >> 1) & 3;
    const int frag = lr * 64 + ((q16 ^ fswz) << 4);
    const int abase = wr * 8192 + frag;
    const int bbase = wc * 4096 + frag;

    f32x4 acc[8][4];
    #pragma unroll
    for (int m = 0; m < 8; ++m)
        #pragma unroll
        for (int n = 0; n < 4; ++n) acc[m][n] = (f32x4)0.0f;

    stage(smem, 0);
    asm volatile("s_waitcnt vmcnt(0)" ::: "memory");
    __builtin_amdgcn_s_barrier();

    for (int t = 0; t < 16; ++t) {
        char* cur = smem + (size_t)(t & 1) * 65536;
        char* nxt = smem + (size_t)((t + 1) & 1) * 65536;

        if (t < 15) stage(nxt, t + 1);

        half8 ah[8], bh[4], bl[4];
        #pragma unroll
        for (int n = 0; n < 4; ++n)
            bh[n] = *(const half8*)(cur + 32768 + bbase + n * 1024);
        #pragma unroll
        for (int m = 0; m < 8; ++m)
            ah[m] = *(const half8*)(cur + abase + m * 1024);
        __builtin_amdgcn_s_setprio(1);
        #pragma unroll
        for (int m = 0; m < 8; ++m)
            #pragma unroll
            for (int n = 0; n < 4; ++n)
                acc[m][n] = __builtin_amdgcn_mfma_f32_16x16x32_f16(ah[m], bh[n], acc[m][n], 0, 0, 0);
        __builtin_amdgcn_s_setprio(0);

        #pragma unroll
        for (int n = 0; n < 4; ++n)
            bl[n] = *(const half8*)(cur + 49152 + bbase + n * 1024);
        __builtin_amdgcn_s_setprio(1);
        #pragma unroll
        for (int m = 0; m < 8; ++m)
            #pragma unroll
            for (int n = 0; n < 4; ++n)
                acc[m][n] = __builtin_amdgcn_mfma_f32_16x16x32_f16(ah[m], bl[n], acc[m][n], 0, 0, 0);
        __builtin_amdgcn_s_setprio(0);

        __builtin_amdgcn_s_setprio(1);
        #pragma unroll
        for (int m = 0; m < 8; ++m) {
            const half8 al = *(const half8*)(cur + 16384 + abase + m * 1024);
            #pragma unroll
            for (int n = 0; n < 4; ++n)
                acc[m][n] = __builtin_amdgcn_mfma_f32_16x16x32_f16(al, bh[n], acc[m][n], 0, 0, 0);
        }
        __builtin_amdgcn_s_setprio(0);

        if (t < 15) {
            asm volatile("s_waitcnt vmcnt(0)" ::: "memory");
            __builtin_amdgcn_s_barrier();
        }
    }

    float* Cz = C + (long)bz * NN * NN;
    #pragma unroll
    for (int m = 0; m < 8; ++m) {
        const int rb = bm + wr * 128 + m * 16 + ((lane >> 4) << 2);
        #pragma unroll
        for (int n = 0; n < 4; ++n) {
            const int gc = bn + wc * 64 + n * 16 + (lane & 15);
            #pragma unroll
            for (int r = 0; r < 4; ++r) {
                const int gr = rb + r;
                float vv = acc[m][n][r] * scale;
                if (gr == gc) vv += fminf(expf(si[gr]), 3.0f);
                Cz[(long)gr * NN + gc] = vv;
            }
        }
    }
}

// ---------------------------------------------------------------------------
// AV GEMM v2-frags: out[b] = attn_h[b] @ vT[b]^T. 256x128 tile, 8 waves
// (4wr x 2wc, 64x64 per wave), 16x16 MFMA, K=2048 (64 steps), gload_lds dbuf
// + pre-swizzled source (conflict-free), per-batch-per-XCD swizzle.
// ---------------------------------------------------------------------------
__global__ __launch_bounds__(512, 2) void av_kernel(
    const halfT* __restrict__ P, const halfT* __restrict__ V,
    float* __restrict__ O)
{
    extern __shared__ __align__(16) char smem[];   // 2 bufs x 24576 B
    // buf layout: A 0 (16 KB, 256 rows) | B 16384 (8 KB, 128 rows)

    const int tid  = threadIdx.x;
    const int lane = tid & 63;
    const int w    = tid >> 6;
    const int wr   = w >> 1, wc = w & 1;  // wave = 64 x 64

    int flat = blockIdx.x;                       // 0..255
    flat = ((flat & 7) << 5) | (flat >> 3);      // batch bz lives on XCD bz
    const int nx = flat & 3, my = (flat >> 2) & 7, bz = flat >> 5;
    const int bm = my * 256, bn = nx * 128;

    const halfT* A = P + (long)bz * NN * NN;
    const halfT* B = V + (long)bz * DD * NN;

    const int s_row   = w * 16 + (lane >> 2);
    const int s_chunk = (lane & 3) ^ ((lane >> 3) & 3);
    const long gA = (long)(bm + s_row) * NN + s_chunk * 8;
    const long gB = (long)(bn + s_row) * NN + s_chunk * 8;
    const int ldst = w * 1024;
    const long rstep = (long)128 * NN;

    auto stage = [&](char* buf, int t) {
        const long kk = (long)t * 32;
        GLOAD16(A + gA + kk,         buf + ldst);
        GLOAD16(A + gA + rstep + kk, buf + 8192 + ldst);
        GLOAD16(B + gB + kk,         buf + 16384 + ldst);
    };

    const int lr  = lane & 15;
    const int q16 = lane >> 4;
    const int frag = lr * 64 + ((q16 ^ ((lr >> 1) & 3)) << 4);
    const int abase = wr * 4096 + frag;   // A rows wr*64, + m*1024
    const int bbase = wc * 4096 + frag;   // B rows wc*64, + j*1024

    f32x4 acc[4][4];
    #pragma unroll
    for (int m = 0; m < 4; ++m)
        #pragma unroll
        for (int j = 0; j < 4; ++j) acc[m][j] = (f32x4)0.0f;

    stage(smem, 0);
    asm volatile("s_waitcnt vmcnt(0)" ::: "memory");
    __builtin_amdgcn_s_barrier();
    __builtin_amdgcn_sched_barrier(0);

    for (int t = 0; t < 64; ++t) {
        char* cur = smem + (size_t)(t & 1) * 24576;
        char* nxt = smem + (size_t)((t + 1) & 1) * 24576;

        if (t < 63) stage(nxt, t + 1);

        half8 ah[4], bh[4];
        #pragma unroll
        for (int m = 0; m < 4; ++m)
            ah[m] = *(const half8*)(cur + abase + m * 1024);
        #pragma unroll
        for (int j = 0; j < 4; ++j)
            bh[j] = *(const half8*)(cur + 16384 + bbase + j * 1024);
        __builtin_amdgcn_s_setprio(1);
        #pragma unroll
        for (int m = 0; m < 4; ++m)
            #pragma unroll
            for (int j = 0; j < 4; ++j)
                acc[m][j] = __builtin_amdgcn_mfma_f32_16x16x32_f16(ah[m], bh[j], acc[m][j], 0, 0, 0);
        __builtin_amdgcn_s_setprio(0);

        if (t < 63) {
            asm volatile("s_waitcnt vmcnt(0)" ::: "memory");
            __builtin_amdgcn_s_barrier();
        }
    }

    float* Oz = O + (long)bz * NN * DD;
    #pragma unroll
    for (int m = 0; m < 4; ++m) {
        const int rb = bm + wr * 64 + m * 16 + (q16 << 2);
        #pragma unroll
        for (int j = 0; j < 4; ++j) {
            const int gc = bn + wc * 64 + j * 16 + lr;
            #pragma unroll
            for (int r = 0; r < 4; ++r)
                Oz[(long)(rb + r) * DD + gc] = acc[m][j][r];
        }
    }
}

// ---------------------------------------------------------------------------
// In-place row softmax + entropy partial + fp16 copy of attn.
// ---------------------------------------------------------------------------
__global__ __launch_bounds__(256) void softmax_entropy_kernel(
    float* __restrict__ attn, _Float16* __restrict__ ah, float* __restrict__ partials)
{
    __shared__ float red[4];
    const long row = blockIdx.x;
    float* p = attn + row * (long)NN;
    _Float16* ph = ah + row * (long)NN;
    const int tid = threadIdx.x;
    const int base = tid * 8;

    float4 va = *(const float4*)(p + base);
    float4 vb = *(const float4*)(p + base + 4);
    float v[8] = {va.x, va.y, va.z, va.w, vb.x, vb.y, vb.z, vb.w};

    float m = v[0];
    #pragma unroll
    for (int i = 1; i < 8; ++i) m = fmaxf(m, v[i]);
    #pragma unroll
    for (int o = 32; o; o >>= 1) m = fmaxf(m, __shfl_xor(m, o, 64));
    if ((tid & 63) == 0) red[tid >> 6] = m;
    __syncthreads();
    m = fmaxf(fmaxf(red[0], red[1]), fmaxf(red[2], red[3]));

    float t[8];
    float s = 0.f;
    #pragma unroll
    for (int i = 0; i < 8; ++i) { t[i] = v[i] - m; v[i] = expf(t[i]); s += v[i]; }
    #pragma unroll
    for (int o = 32; o; o >>= 1) s += __shfl_xor(s, o, 64);
    __syncthreads();
    if ((tid & 63) == 0) red[tid >> 6] = s;
    __syncthreads();
    s = red[0] + red[1] + red[2] + red[3];

    const float inv = 1.0f / s;
    const float lns = logf(s);
    float e = 0.f;
    float pv[8];
    #pragma unroll
    for (int i = 0; i < 8; ++i) {
        pv[i] = v[i] * inv;
        e = fmaf(pv[i], t[i] - lns, e);
    }
    *(float4*)(p + base)     = make_float4(pv[0], pv[1], pv[2], pv[3]);
    *(float4*)(p + base + 4) = make_float4(pv[4], pv[5], pv[6], pv[7]);
    half8 h;
    #pragma unroll
    for (int i = 0; i < 8; ++i) h[i] = (_Float16)pv[i];
    *(half8*)(ph + base) = h;

    #pragma unroll
    for (int o = 32; o; o >>= 1) e += __shfl_xor(e, o, 64);
    __syncthreads();
    if ((tid & 63) == 0) red[tid >> 6] = e;
    __syncthreads();
    if (tid == 0) partials[row] = red[0] + red[1] + red[2] + red[3];
}

__global__ __launch_bounds__(256) void ent_reduce_kernel(
    const float* __restrict__ partials, float* __restrict__ ent)
{
    __shared__ float red[4];
    float s = 0.f;
    for (int i = threadIdx.x; i < BB * NN; i += 256) s += partials[i];
    #pragma unroll
    for (int o = 32; o; o >>= 1) s += __shfl_xor(s, o, 64);
    if ((threadIdx.x & 63) == 0) red[threadIdx.x >> 6] = s;
    __syncthreads();
    if (threadIdx.x == 0)
        *ent = -(red[0] + red[1] + red[2] + red[3]) / (float)(BB * NN);
}

extern "C" void kernel_launch(void* const* d_in, const int* in_sizes, int n_in,
                              void* d_out, int out_size, void* d_ws, size_t ws_size,
                              hipStream_t stream) {
    const float* query = (const float*)d_in[0];
    const float* key   = (const float*)d_in[1];
    const float* value = (const float*)d_in[2];
    const float* Wq    = (const float*)d_in[3];
    const float* Wk    = (const float*)d_in[4];
    const float* Wv    = (const float*)d_in[5];
    const float* si    = (const float*)d_in[6];

    float* out  = (float*)d_out;                        // [B,N,D]
    float* attn = out + (size_t)BB * NN * DD;           // [B,N,N]
    float* ent  = attn + (size_t)BB * NN * NN;          // scalar

    const size_t NK = (size_t)BB * NN * DD;             // 8.39M elements
    _Float16* ws16 = (_Float16*)d_ws;
    _Float16* qh = ws16;            // 16.8 MB each
    _Float16* ql = qh + NK;
    _Float16* kh = ql + NK;
    _Float16* kl = kh + NK;
    _Float16* vT = kl + NK;         // vT fp16 [b][512][2048]
    _Float16* WqhT = vT + NK;       // 0.5 MB each
    _Float16* WqlT = WqhT + DD * DD;
    _Float16* WkhT = WqlT + DD * DD;
    _Float16* WklT = WkhT + DD * DD;
    _Float16* WvhT = WklT + DD * DD;
    float* partials = (float*)(WvhT + DD * DD);         // 64 KB
    _Float16* attn_h = ws16;        // 67 MB, aliases qh..kl (dead after scores)

    const dim3 blk(256);
    const float inv_sqrt_d = 0.044194173824159216f;     // 1/sqrt(512)

    wsplit_kernel<<<dim3(8, 8, 3), blk, 0, stream>>>(Wq, Wk, Wv,
        WqhT, WqlT, WkhT, WklT, WvhT);

    // merged q/k projections, 256x128-tile 2-phase pipeline
    projqk_kernel<<<dim3(512), dim3(512), 98304, stream>>>(
        query, key, WqhT, WqlT, WkhT, WklT, qh, ql, kh, kl);
    // v projection, 1-product, writes vT fp16
    vproj_kernel<<<dim3(4, 128, 1), blk, 0, stream>>>(value, WvhT, vT);

    // scores = q k^T / sqrt(d) + diag(min(exp(si),3))  [v2 proven]
    scores256_kernel<<<dim3(8, 8, 8), dim3(512), 131072, stream>>>(
        qh, ql, kh, kl, attn, si, inv_sqrt_d);

    softmax_entropy_kernel<<<dim3(BB * NN), blk, 0, stream>>>(attn, attn_h, partials);
    ent_reduce_kernel<<<dim3(1), blk, 0, stream>>>(partials, ent);

    // out = attn @ v  [256x128 tile, v2 fragments]
    av_kernel<<<dim3(256), dim3(512), 49152, stream>>>(attn_h, vT, out);
}